// Round 1
// baseline (2606.516 us; speedup 1.0000x reference)
//
#include <hip/hip_runtime.h>
#include <hip/hip_bf16.h>

// ---------------------------------------------------------------------------
// T5 encoder self-attention, fp32 baseline.
//   B=2, S=2048, Dm=1024, H=16, Dk=64, NUM_BUCKETS=32, MAX_DISTANCE=128
// Pipeline:
//   1) bias_table_kernel: tab[h][delta+2048] = rel_emb[bucket(delta)][h]
//   2) gemm_qkv (z=3): q/k/v = x @ w{q,k,v}, scattered to [B,H,S,Dk]
//   3) attn_kernel: flash-style online softmax per (b,h,16 q-rows)
//   4) gemm_out: out = ctx @ wo
// ---------------------------------------------------------------------------

#define S_LEN 2048
#define NH    16
#define DK    64
#define DMODEL 1024

// ------------------------- bias table --------------------------------------
// Reference bucket: rel_pos = k - q; n = q - k; ret = (n<0)*16; n = |n|;
// n<8 -> inner=n else inner = 8 + #(thresholds <= n), thresholds derived to
// match fp32 log arithmetic exactly: {12,16,23,32,46,64,91}, capped at 15.
__global__ __launch_bounds__(256) void bias_table_kernel(
    const float* __restrict__ rel_emb, float* __restrict__ tab)
{
    int idx = blockIdx.x * 256 + threadIdx.x;   // 0..65535
    int h = idx >> 12;
    int t = idx & 4095;
    int rp = t - 2048;          // rel_pos = k - q
    int n = -rp;                // q - k
    int ret = 0;
    if (n < 0) { ret = 16; n = -n; }
    int inner;
    if (n < 8) {
        inner = n;
    } else {
        inner = 8 + (n >= 12) + (n >= 16) + (n >= 23) + (n >= 32)
                  + (n >= 46) + (n >= 64) + (n >= 91);
        if (inner > 15) inner = 15;
    }
    tab[h * 4096 + t] = rel_emb[(ret + inner) * NH + h];
}

// ------------------------- fp32 tiled GEMM ---------------------------------
#define BM 128
#define BN 128
#define BK 16

// C[M=4096, N=1024] = X[4096,1024] @ W[1024,1024]; scatter to [B,H,S,Dk]
__global__ __launch_bounds__(256) void gemm_qkv(
    const float* __restrict__ X,
    const float* __restrict__ Wq, const float* __restrict__ Wk,
    const float* __restrict__ Wv,
    float* __restrict__ Qt, float* __restrict__ Kt, float* __restrict__ Vt)
{
    const int Kd = DMODEL, N = DMODEL;
    const float* W = (blockIdx.z == 0) ? Wq : (blockIdx.z == 1 ? Wk : Wv);
    float* O       = (blockIdx.z == 0) ? Qt : (blockIdx.z == 1 ? Kt : Vt);

    __shared__ float As[BK][BM];
    __shared__ float Ws[BK][BN];

    const int tid = threadIdx.x;
    const int tx = tid & 15, ty = tid >> 4;
    const int bm = blockIdx.y * BM, bn = blockIdx.x * BN;

    float acc[8][8];
    #pragma unroll
    for (int i = 0; i < 8; i++)
        #pragma unroll
        for (int j = 0; j < 8; j++) acc[i][j] = 0.f;

    for (int k0 = 0; k0 < Kd; k0 += BK) {
        // A tile: 128 rows x 16 cols
        {
            int row = tid >> 2, c4 = tid & 3;
            float4 v0 = *(const float4*)&X[(long)(bm + row) * Kd + k0 + c4 * 4];
            float4 v1 = *(const float4*)&X[(long)(bm + row + 64) * Kd + k0 + c4 * 4];
            As[c4 * 4 + 0][row] = v0.x; As[c4 * 4 + 1][row] = v0.y;
            As[c4 * 4 + 2][row] = v0.z; As[c4 * 4 + 3][row] = v0.w;
            As[c4 * 4 + 0][row + 64] = v1.x; As[c4 * 4 + 1][row + 64] = v1.y;
            As[c4 * 4 + 2][row + 64] = v1.z; As[c4 * 4 + 3][row + 64] = v1.w;
        }
        // W tile: 16 rows x 128 cols
        {
            int wr = tid >> 5, wc = tid & 31;
            *(float4*)&Ws[wr][wc * 4] =
                *(const float4*)&W[(long)(k0 + wr) * N + bn + wc * 4];
            *(float4*)&Ws[wr + 8][wc * 4] =
                *(const float4*)&W[(long)(k0 + wr + 8) * N + bn + wc * 4];
        }
        __syncthreads();

        #pragma unroll
        for (int kk = 0; kk < BK; kk++) {
            float a[8], bb[8];
            *(float4*)&a[0]  = *(float4*)&As[kk][ty * 8];
            *(float4*)&a[4]  = *(float4*)&As[kk][ty * 8 + 4];
            *(float4*)&bb[0] = *(float4*)&Ws[kk][tx * 8];
            *(float4*)&bb[4] = *(float4*)&Ws[kk][tx * 8 + 4];
            #pragma unroll
            for (int i = 0; i < 8; i++)
                #pragma unroll
                for (int j = 0; j < 8; j++)
                    acc[i][j] = fmaf(a[i], bb[j], acc[i][j]);
        }
        __syncthreads();
    }

    // epilogue: scatter to [B, H, S, Dk]
    #pragma unroll
    for (int i = 0; i < 8; i++) {
        int row = bm + ty * 8 + i;
        int b = row >> 11, s = row & 2047;
        #pragma unroll
        for (int j = 0; j < 8; j += 4) {
            int col = bn + tx * 8 + j;
            int h = col >> 6, d = col & 63;
            float4 v = make_float4(acc[i][j], acc[i][j + 1], acc[i][j + 2], acc[i][j + 3]);
            *(float4*)&O[(((long)(b * NH + h)) * S_LEN + s) * DK + d] = v;
        }
    }
}

// out[M=4096, N=1024] = CtxIn[4096,1024] @ Wo[1024,1024], plain row-major out
__global__ __launch_bounds__(256) void gemm_out(
    const float* __restrict__ X, const float* __restrict__ W,
    float* __restrict__ O)
{
    const int Kd = DMODEL, N = DMODEL;
    __shared__ float As[BK][BM];
    __shared__ float Ws[BK][BN];

    const int tid = threadIdx.x;
    const int tx = tid & 15, ty = tid >> 4;
    const int bm = blockIdx.y * BM, bn = blockIdx.x * BN;

    float acc[8][8];
    #pragma unroll
    for (int i = 0; i < 8; i++)
        #pragma unroll
        for (int j = 0; j < 8; j++) acc[i][j] = 0.f;

    for (int k0 = 0; k0 < Kd; k0 += BK) {
        {
            int row = tid >> 2, c4 = tid & 3;
            float4 v0 = *(const float4*)&X[(long)(bm + row) * Kd + k0 + c4 * 4];
            float4 v1 = *(const float4*)&X[(long)(bm + row + 64) * Kd + k0 + c4 * 4];
            As[c4 * 4 + 0][row] = v0.x; As[c4 * 4 + 1][row] = v0.y;
            As[c4 * 4 + 2][row] = v0.z; As[c4 * 4 + 3][row] = v0.w;
            As[c4 * 4 + 0][row + 64] = v1.x; As[c4 * 4 + 1][row + 64] = v1.y;
            As[c4 * 4 + 2][row + 64] = v1.z; As[c4 * 4 + 3][row + 64] = v1.w;
        }
        {
            int wr = tid >> 5, wc = tid & 31;
            *(float4*)&Ws[wr][wc * 4] =
                *(const float4*)&W[(long)(k0 + wr) * N + bn + wc * 4];
            *(float4*)&Ws[wr + 8][wc * 4] =
                *(const float4*)&W[(long)(k0 + wr + 8) * N + bn + wc * 4];
        }
        __syncthreads();

        #pragma unroll
        for (int kk = 0; kk < BK; kk++) {
            float a[8], bb[8];
            *(float4*)&a[0]  = *(float4*)&As[kk][ty * 8];
            *(float4*)&a[4]  = *(float4*)&As[kk][ty * 8 + 4];
            *(float4*)&bb[0] = *(float4*)&Ws[kk][tx * 8];
            *(float4*)&bb[4] = *(float4*)&Ws[kk][tx * 8 + 4];
            #pragma unroll
            for (int i = 0; i < 8; i++)
                #pragma unroll
                for (int j = 0; j < 8; j++)
                    acc[i][j] = fmaf(a[i], bb[j], acc[i][j]);
        }
        __syncthreads();
    }

    #pragma unroll
    for (int i = 0; i < 8; i++) {
        int row = bm + ty * 8 + i;
        #pragma unroll
        for (int j = 0; j < 8; j += 4) {
            int col = bn + tx * 8 + j;
            float4 v = make_float4(acc[i][j], acc[i][j + 1], acc[i][j + 2], acc[i][j + 3]);
            *(float4*)&O[(long)row * N + col] = v;
        }
    }
}

// ------------------------- attention ---------------------------------------
#define QB 16     // q rows per block
#define KT 64     // keys per tile
#define PAD 68    // LDS row stride in floats (64 + 4): keeps reads <=2-way

// Thread map: 256 threads; r = tid>>4 (q-row 0..15), c = tid&15.
// Scores: thread (r,c) handles keys {c, c+16, c+32, c+48} of the tile.
// Context: thread (r,c) accumulates dims d = c*4 .. c*4+3.
__global__ __launch_bounds__(256) void attn_kernel(
    const float* __restrict__ Qt, const float* __restrict__ Kt,
    const float* __restrict__ Vt, const float* __restrict__ tab,
    float* __restrict__ ctx)
{
    __shared__ float Qs[QB * PAD];
    __shared__ float Ks[KT * PAD];
    __shared__ float Vs[KT * PAD];
    __shared__ float sc[QB * PAD];
    __shared__ float red[QB * 16];
    __shared__ float row_m[QB], row_l[QB];

    const int tid = threadIdx.x;
    const int r = tid >> 4, c = tid & 15;
    const int blk = blockIdx.x;
    const int qb = blk & 127;          // S/QB = 128
    const int h  = (blk >> 7) & 15;
    const int b  = blk >> 11;

    const long base = ((long)(b * NH + h)) * S_LEN * DK;
    const float* Qh = Qt + base;
    const float* Kh = Kt + base;
    const float* Vh = Vt + base;
    const float* th = tab + h * 4096;
    const int qg = qb * QB + r;

    // load Q block: 16 rows x 16 float4 = one float4/thread
    *(float4*)&Qs[r * PAD + c * 4] =
        *(const float4*)&Qh[(long)qg * DK + c * 4];
    if (tid < QB) { row_m[tid] = -1e30f; row_l[tid] = 0.f; }

    float4 acc = make_float4(0.f, 0.f, 0.f, 0.f);
    __syncthreads();

    for (int kt0 = 0; kt0 < S_LEN; kt0 += KT) {
        // stage K,V tiles (64 rows x 64 floats each)
        for (int t = tid; t < KT * 16; t += 256) {
            int row = t >> 4, c4 = t & 15;
            *(float4*)&Ks[row * PAD + c4 * 4] =
                *(const float4*)&Kh[(long)(kt0 + row) * DK + c4 * 4];
            *(float4*)&Vs[row * PAD + c4 * 4] =
                *(const float4*)&Vh[(long)(kt0 + row) * DK + c4 * 4];
        }
        __syncthreads();   // (E) tiles ready

        // scores for keys c+16j, seeded with bias
        float s0, s1, s2, s3;
        {
            int d0 = kt0 + c - qg + 2048;   // in [1, 4095]
            s0 = th[d0]; s1 = th[d0 + 16]; s2 = th[d0 + 32]; s3 = th[d0 + 48];
        }
        #pragma unroll
        for (int d4 = 0; d4 < 16; d4++) {
            float4 qv = *(float4*)&Qs[r * PAD + d4 * 4];
            float4 k0 = *(float4*)&Ks[(c     ) * PAD + d4 * 4];
            float4 k1 = *(float4*)&Ks[(c + 16) * PAD + d4 * 4];
            float4 k2 = *(float4*)&Ks[(c + 32) * PAD + d4 * 4];
            float4 k3 = *(float4*)&Ks[(c + 48) * PAD + d4 * 4];
            s0 += qv.x * k0.x + qv.y * k0.y + qv.z * k0.z + qv.w * k0.w;
            s1 += qv.x * k1.x + qv.y * k1.y + qv.z * k1.z + qv.w * k1.w;
            s2 += qv.x * k2.x + qv.y * k2.y + qv.z * k2.z + qv.w * k2.w;
            s3 += qv.x * k3.x + qv.y * k3.y + qv.z * k3.z + qv.w * k3.w;
        }
        float lmax = fmaxf(fmaxf(s0, s1), fmaxf(s2, s3));
        red[r * 16 + c] = lmax;
        __syncthreads();   // (A) tile maxes visible

        float m_old = row_m[r];
        float m_new = m_old;
        #pragma unroll
        for (int i = 0; i < 16; i++) m_new = fmaxf(m_new, red[r * 16 + i]);
        float alpha = expf(m_old - m_new);
        float p0 = expf(s0 - m_new), p1 = expf(s1 - m_new);
        float p2 = expf(s2 - m_new), p3 = expf(s3 - m_new);
        float lsum = p0 + p1 + p2 + p3;
        __syncthreads();   // (B) everyone done reading red / row_m

        sc[r * PAD + c]      = p0;
        sc[r * PAD + c + 16] = p1;
        sc[r * PAD + c + 32] = p2;
        sc[r * PAD + c + 48] = p3;
        red[r * 16 + c] = lsum;
        acc.x *= alpha; acc.y *= alpha; acc.z *= alpha; acc.w *= alpha;
        __syncthreads();   // (C) p's and partial sums visible

        #pragma unroll
        for (int k = 0; k < KT; k++) {
            float p = sc[r * PAD + k];
            float4 vv = *(float4*)&Vs[k * PAD + c * 4];
            acc.x = fmaf(p, vv.x, acc.x);
            acc.y = fmaf(p, vv.y, acc.y);
            acc.z = fmaf(p, vv.z, acc.z);
            acc.w = fmaf(p, vv.w, acc.w);
        }
        if (c == 0) {
            float ls = 0.f;
            #pragma unroll
            for (int i = 0; i < 16; i++) ls += red[r * 16 + i];
            row_l[r] = row_l[r] * alpha + ls;
            row_m[r] = m_new;
        }
        __syncthreads();   // (D) row stats committed; tiles reusable
    }

    float inv = 1.0f / row_l[r];
    int orow = b * S_LEN + qg;
    float4 o = make_float4(acc.x * inv, acc.y * inv, acc.z * inv, acc.w * inv);
    *(float4*)&ctx[(long)orow * DMODEL + h * DK + c * 4] = o;
}

// ------------------------- launcher ----------------------------------------
extern "C" void kernel_launch(void* const* d_in, const int* in_sizes, int n_in,
                              void* d_out, int out_size, void* d_ws, size_t ws_size,
                              hipStream_t stream)
{
    const float* x    = (const float*)d_in[0];
    const float* wq   = (const float*)d_in[1];
    const float* wk   = (const float*)d_in[2];
    const float* wv   = (const float*)d_in[3];
    const float* wo   = (const float*)d_in[4];
    const float* rel  = (const float*)d_in[5];

    float* ws  = (float*)d_ws;
    float* qt  = ws;                    // [B,H,S,Dk] = 4,194,304 floats
    float* kt  = qt + 4194304;
    float* vt  = kt + 4194304;
    float* ctx = vt + 4194304;          // [B*S, 1024]
    float* tab = ctx + 4194304;         // [16, 4096]

    bias_table_kernel<<<dim3(256), dim3(256), 0, stream>>>(rel, tab);
    gemm_qkv<<<dim3(8, 32, 3), dim3(256), 0, stream>>>(x, wq, wk, wv, qt, kt, vt);
    attn_kernel<<<dim3(4096), dim3(256), 0, stream>>>(qt, kt, vt, tab, ctx);
    gemm_out<<<dim3(8, 32, 1), dim3(256), 0, stream>>>(ctx, wo, (float*)d_out);
}

// Round 2
// 710.815 us; speedup vs baseline: 3.6669x; 3.6669x over previous
//
#include <hip/hip_runtime.h>
#include <hip/hip_bf16.h>

typedef __attribute__((ext_vector_type(8))) short bf16x8;
typedef __attribute__((ext_vector_type(4))) float f32x4;
typedef unsigned short u16;
typedef unsigned int u32;

#define S_LEN 2048
#define NH    16
#define DK    64
#define DMODEL 1024

__device__ __forceinline__ u16 f2bf(float f) {
    u32 u = __float_as_uint(f);
    return (u16)((u + 0x7FFFu + ((u >> 16) & 1u)) >> 16);
}
__device__ __forceinline__ float bf2f(u16 s) {
    return __uint_as_float(((u32)s) << 16);
}

// ------------------------- bias table --------------------------------------
// Integer-exact replica of the reference fp32 bucket math; thresholds
// {12,16,23,32,46,64,91} verified against fp32 log arithmetic.
__global__ __launch_bounds__(256) void bias_table_kernel(
    const float* __restrict__ rel_emb, float* __restrict__ tab)
{
    int idx = blockIdx.x * 256 + threadIdx.x;   // 0..65535
    int h = idx >> 12;
    int t = idx & 4095;
    int rp = t - 2048;          // rel_pos = k - q
    int n = -rp;                // q - k
    int ret = 0;
    if (n < 0) { ret = 16; n = -n; }
    int inner;
    if (n < 8) {
        inner = n;
    } else {
        inner = 8 + (n >= 12) + (n >= 16) + (n >= 23) + (n >= 32)
                  + (n >= 46) + (n >= 64) + (n >= 91);
        if (inner > 15) inner = 15;
    }
    tab[h * 4096 + t] = rel_emb[(ret + inner) * NH + h];
}

// ------------------------- fp32 tiled GEMM (QKV) ---------------------------
#define BM 128
#define BN 128
#define BK 16

__global__ __launch_bounds__(256) void gemm_qkv(
    const float* __restrict__ X,
    const float* __restrict__ Wq, const float* __restrict__ Wk,
    const float* __restrict__ Wv,
    u16* __restrict__ Qhi, u16* __restrict__ Qlo,
    u16* __restrict__ Khi, u16* __restrict__ Klo,
    u16* __restrict__ Vb)
{
    const int Kd = DMODEL, N = DMODEL;
    const float* W = (blockIdx.z == 0) ? Wq : (blockIdx.z == 1 ? Wk : Wv);

    __shared__ __align__(16) float As[BK][BM];
    __shared__ __align__(16) float Ws[BK][BN];

    const int tid = threadIdx.x;
    const int tx = tid & 15, ty = tid >> 4;
    const int bm = blockIdx.y * BM, bn = blockIdx.x * BN;

    float acc[8][8];
    #pragma unroll
    for (int i = 0; i < 8; i++)
        #pragma unroll
        for (int j = 0; j < 8; j++) acc[i][j] = 0.f;

    for (int k0 = 0; k0 < Kd; k0 += BK) {
        {
            int row = tid >> 2, c4 = tid & 3;
            float4 v0 = *(const float4*)&X[(long)(bm + row) * Kd + k0 + c4 * 4];
            float4 v1 = *(const float4*)&X[(long)(bm + row + 64) * Kd + k0 + c4 * 4];
            As[c4 * 4 + 0][row] = v0.x; As[c4 * 4 + 1][row] = v0.y;
            As[c4 * 4 + 2][row] = v0.z; As[c4 * 4 + 3][row] = v0.w;
            As[c4 * 4 + 0][row + 64] = v1.x; As[c4 * 4 + 1][row + 64] = v1.y;
            As[c4 * 4 + 2][row + 64] = v1.z; As[c4 * 4 + 3][row + 64] = v1.w;
        }
        {
            int wr = tid >> 5, wc = tid & 31;
            *(float4*)&Ws[wr][wc * 4] =
                *(const float4*)&W[(long)(k0 + wr) * N + bn + wc * 4];
            *(float4*)&Ws[wr + 8][wc * 4] =
                *(const float4*)&W[(long)(k0 + wr + 8) * N + bn + wc * 4];
        }
        __syncthreads();

        #pragma unroll
        for (int kk = 0; kk < BK; kk++) {
            float a[8], bb[8];
            *(float4*)&a[0]  = *(float4*)&As[kk][ty * 8];
            *(float4*)&a[4]  = *(float4*)&As[kk][ty * 8 + 4];
            *(float4*)&bb[0] = *(float4*)&Ws[kk][tx * 8];
            *(float4*)&bb[4] = *(float4*)&Ws[kk][tx * 8 + 4];
            #pragma unroll
            for (int i = 0; i < 8; i++)
                #pragma unroll
                for (int j = 0; j < 8; j++)
                    acc[i][j] = fmaf(a[i], bb[j], acc[i][j]);
        }
        __syncthreads();
    }

    // epilogue: bf16 hi/lo split, scatter to [B,H,S,Dk]
    #pragma unroll
    for (int i = 0; i < 8; i++) {
        int row = bm + ty * 8 + i;
        int bb = row >> 11, s = row & 2047;
        int col0 = bn + tx * 8;
        int hh = col0 >> 6, d0 = col0 & 63;     // 8 consecutive d, one head
        long base = (((long)(bb * NH + hh)) * S_LEN + s) * DK + d0;
        u16 hi[8], lo[8];
        #pragma unroll
        for (int j = 0; j < 8; j++) {
            float f = acc[i][j];
            u16 hb = f2bf(f);
            hi[j] = hb;
            lo[j] = f2bf(f - bf2f(hb));
        }
        if (blockIdx.z == 2) {
            *(ushort4*)&Vb[base]     = make_ushort4(hi[0], hi[1], hi[2], hi[3]);
            *(ushort4*)&Vb[base + 4] = make_ushort4(hi[4], hi[5], hi[6], hi[7]);
        } else {
            u16* OH = (blockIdx.z == 0) ? Qhi : Khi;
            u16* OL = (blockIdx.z == 0) ? Qlo : Klo;
            *(ushort4*)&OH[base]     = make_ushort4(hi[0], hi[1], hi[2], hi[3]);
            *(ushort4*)&OH[base + 4] = make_ushort4(hi[4], hi[5], hi[6], hi[7]);
            *(ushort4*)&OL[base]     = make_ushort4(lo[0], lo[1], lo[2], lo[3]);
            *(ushort4*)&OL[base + 4] = make_ushort4(lo[4], lo[5], lo[6], lo[7]);
        }
    }
}

// ------------------------- V transpose: [B,H,S,Dk] -> [B,H,Dk,S] -----------
__global__ __launch_bounds__(256) void transpose_v(
    const u16* __restrict__ Vb, u16* __restrict__ VT)
{
    __shared__ __align__(16) u16 t[64 * 68];
    const int blk = blockIdx.x;           // 1024 = 32 s-tiles x 32 bh
    const int st = blk & 31, bh = blk >> 5;
    const int s0 = st * 64;
    const u16* src = Vb + ((long)bh * S_LEN + s0) * DK;
    u16* dst = VT + (long)bh * DK * S_LEN;
    const int tid = threadIdx.x;

    #pragma unroll
    for (int u = 0; u < 2; u++) {
        int w = tid + u * 256;
        int s = w >> 3, c8 = (w & 7) * 8;
        ushort4 a = *(const ushort4*)&src[s * DK + c8];
        ushort4 b = *(const ushort4*)&src[s * DK + c8 + 4];
        *(ushort4*)&t[s * 68 + c8] = a;          // stride 68: 8B-aligned
        *(ushort4*)&t[s * 68 + c8 + 4] = b;
    }
    __syncthreads();
    #pragma unroll
    for (int u = 0; u < 2; u++) {
        int w = tid + u * 256;
        int d = w >> 3, sc8 = (w & 7) * 8;
        u16 tmp[8];
        #pragma unroll
        for (int j = 0; j < 8; j++) tmp[j] = t[(sc8 + j) * 68 + d];
        *(ushort4*)&dst[(long)d * S_LEN + s0 + sc8]     = make_ushort4(tmp[0], tmp[1], tmp[2], tmp[3]);
        *(ushort4*)&dst[(long)d * S_LEN + s0 + sc8 + 4] = make_ushort4(tmp[4], tmp[5], tmp[6], tmp[7]);
    }
}

// ------------------------- MFMA flash attention ----------------------------
// Block: 256 thr = 4 waves, 64 q-rows per block (16 per wave), one (b,h).
// K-tiles of 64 keys staged in LDS (bf16 hi/lo) + V^T tile + 128-entry bias.
// S = Qhi*Khi + Qlo*Khi + Qhi*Klo  (fp32-accurate scores).
#define APAD 72   // LDS row stride (bf16): 16B-aligned, 2-way-conflict max

__global__ __launch_bounds__(256, 4) void attn_mfma(
    const u16* __restrict__ Qhi, const u16* __restrict__ Qlo,
    const u16* __restrict__ Khi, const u16* __restrict__ Klo,
    const u16* __restrict__ VT, const float* __restrict__ tab,
    float* __restrict__ ctx)
{
    __shared__ __align__(16) u16 KsH[64 * APAD];
    __shared__ __align__(16) u16 KsL[64 * APAD];
    __shared__ __align__(16) u16 Vs[64 * APAD];    // [dim][key]
    __shared__ __align__(16) u16 Ps[64 * APAD];    // wave-private 16-row slabs
    __shared__ float biasS[128];

    const int tid = threadIdx.x;
    const int wv = tid >> 6, lane = tid & 63;
    const int g = lane >> 4, li = lane & 15;
    const int qblk = blockIdx.x & 31;
    const int h = (blockIdx.x >> 5) & 15;
    const int b = blockIdx.x >> 9;
    const int q0 = qblk * 64;
    const long bh = b * NH + h;

    const u16* KhG = Khi + bh * (S_LEN * DK);
    const u16* KlG = Klo + bh * (S_LEN * DK);
    const u16* VtG = VT  + bh * (DK * S_LEN);
    const float* th = tab + h * 4096;

    // Q fragments: A-layout m=li, k=g*8+j (+32 for kstep 1)
    bf16x8 qh0, qh1, ql0, ql1;
    {
        long qrow = bh * S_LEN + q0 + wv * 16 + li;
        const u16* ph = Qhi + qrow * DK + g * 8;
        const u16* pl = Qlo + qrow * DK + g * 8;
        qh0 = *(const bf16x8*)ph;  qh1 = *(const bf16x8*)(ph + 32);
        ql0 = *(const bf16x8*)pl;  ql1 = *(const bf16x8*)(pl + 32);
    }

    f32x4 Oc[4];
    float mP[4], lR[4];
    #pragma unroll
    for (int n = 0; n < 4; n++) { Oc[n] = (f32x4){0.f, 0.f, 0.f, 0.f}; }
    #pragma unroll
    for (int r = 0; r < 4; r++) { mP[r] = -1e30f; lR[r] = 0.f; }
    const int qr = wv * 16 + g * 4;   // lane's base row within the 64-row block

    for (int kt0 = 0; kt0 < S_LEN; kt0 += 64) {
        // ---- stage K hi/lo + V^T tiles, and bias slice ----
        #pragma unroll
        for (int u = 0; u < 2; u++) {
            int w = tid + u * 256;
            int row = w >> 3, c8 = (w & 7) * 8;
            *(uint4*)&KsH[row * APAD + c8] =
                *(const uint4*)&KhG[(long)(kt0 + row) * DK + c8];
            *(uint4*)&KsL[row * APAD + c8] =
                *(const uint4*)&KlG[(long)(kt0 + row) * DK + c8];
            *(uint4*)&Vs[row * APAD + c8] =
                *(const uint4*)&VtG[(long)row * S_LEN + kt0 + c8];
        }
        if (tid < 128) {
            int idx = kt0 + tid - 63 - q0 + 2048;
            idx = idx < 0 ? 0 : (idx > 4095 ? 4095 : idx);
            biasS[tid] = th[idx];
        }
        __syncthreads();

        // ---- scores: 4 n-tiles of 16 keys ----
        f32x4 Sa[4];
        #pragma unroll
        for (int n = 0; n < 4; n++) {
            const u16* kh = &KsH[(n * 16 + li) * APAD + g * 8];
            const u16* kl = &KsL[(n * 16 + li) * APAD + g * 8];
            bf16x8 bh0 = *(const bf16x8*)kh, bh1 = *(const bf16x8*)(kh + 32);
            bf16x8 bl0 = *(const bf16x8*)kl, bl1 = *(const bf16x8*)(kl + 32);
            f32x4 s = (f32x4){0.f, 0.f, 0.f, 0.f};
            s = __builtin_amdgcn_mfma_f32_16x16x32_bf16(qh0, bh0, s, 0, 0, 0);
            s = __builtin_amdgcn_mfma_f32_16x16x32_bf16(ql0, bh0, s, 0, 0, 0);
            s = __builtin_amdgcn_mfma_f32_16x16x32_bf16(qh0, bl0, s, 0, 0, 0);
            s = __builtin_amdgcn_mfma_f32_16x16x32_bf16(qh1, bh1, s, 0, 0, 0);
            s = __builtin_amdgcn_mfma_f32_16x16x32_bf16(ql1, bh1, s, 0, 0, 0);
            s = __builtin_amdgcn_mfma_f32_16x16x32_bf16(qh1, bl1, s, 0, 0, 0);
            Sa[n] = s;
        }

        // ---- bias + online softmax (rows = qr+r, cols across 16-lane group)
        #pragma unroll
        for (int n = 0; n < 4; n++)
            #pragma unroll
            for (int r = 0; r < 4; r++)
                Sa[n][r] += biasS[n * 16 + li - qr - r + 63];

        float rmx[4];
        #pragma unroll
        for (int r = 0; r < 4; r++)
            rmx[r] = fmaxf(fmaxf(Sa[0][r], Sa[1][r]), fmaxf(Sa[2][r], Sa[3][r]));
        #pragma unroll
        for (int mk = 1; mk < 16; mk <<= 1)
            #pragma unroll
            for (int r = 0; r < 4; r++)
                rmx[r] = fmaxf(rmx[r], __shfl_xor(rmx[r], mk));

        float alpha[4];
        #pragma unroll
        for (int r = 0; r < 4; r++) {
            float mn = fmaxf(mP[r], rmx[r]);
            alpha[r] = __expf(mP[r] - mn);
            mP[r] = mn;
        }
        #pragma unroll
        for (int n = 0; n < 4; n++)
            #pragma unroll
            for (int r = 0; r < 4; r++)
                Sa[n][r] = __expf(Sa[n][r] - mP[r]);

        float ls[4];
        #pragma unroll
        for (int r = 0; r < 4; r++)
            ls[r] = Sa[0][r] + Sa[1][r] + Sa[2][r] + Sa[3][r];
        #pragma unroll
        for (int mk = 1; mk < 16; mk <<= 1)
            #pragma unroll
            for (int r = 0; r < 4; r++)
                ls[r] += __shfl_xor(ls[r], mk);
        #pragma unroll
        for (int r = 0; r < 4; r++)
            lR[r] = lR[r] * alpha[r] + ls[r];
        #pragma unroll
        for (int n = 0; n < 4; n++)
            #pragma unroll
            for (int r = 0; r < 4; r++)
                Oc[n][r] *= alpha[r];

        // ---- write P (bf16) into wave-private LDS slab ----
        #pragma unroll
        for (int n = 0; n < 4; n++)
            #pragma unroll
            for (int r = 0; r < 4; r++)
                Ps[(qr + r) * APAD + n * 16 + li] = f2bf(Sa[n][r]);
        __syncthreads();

        // ---- O += P * V ----
        {
            const u16* pp = &Ps[(wv * 16 + li) * APAD + g * 8];
            bf16x8 p0 = *(const bf16x8*)pp, p1 = *(const bf16x8*)(pp + 32);
            #pragma unroll
            for (int n = 0; n < 4; n++) {
                const u16* vp = &Vs[(n * 16 + li) * APAD + g * 8];
                bf16x8 v0 = *(const bf16x8*)vp, v1 = *(const bf16x8*)(vp + 32);
                Oc[n] = __builtin_amdgcn_mfma_f32_16x16x32_bf16(p0, v0, Oc[n], 0, 0, 0);
                Oc[n] = __builtin_amdgcn_mfma_f32_16x16x32_bf16(p1, v1, Oc[n], 0, 0, 0);
            }
        }
        __syncthreads();   // all waves done with K/V/P before next staging
    }

    float inv[4];
    #pragma unroll
    for (int r = 0; r < 4; r++) inv[r] = 1.0f / lR[r];
    #pragma unroll
    for (int n = 0; n < 4; n++)
        #pragma unroll
        for (int r = 0; r < 4; r++)
            ctx[((long)(b * S_LEN + q0 + qr + r)) * DMODEL + h * DK + n * 16 + li] =
                Oc[n][r] * inv[r];
}

// ------------------------- output GEMM (fp32) ------------------------------
__global__ __launch_bounds__(256) void gemm_out(
    const float* __restrict__ X, const float* __restrict__ W,
    float* __restrict__ O)
{
    const int Kd = DMODEL, N = DMODEL;
    __shared__ __align__(16) float As[BK][BM];
    __shared__ __align__(16) float Ws[BK][BN];

    const int tid = threadIdx.x;
    const int tx = tid & 15, ty = tid >> 4;
    const int bm = blockIdx.y * BM, bn = blockIdx.x * BN;

    float acc[8][8];
    #pragma unroll
    for (int i = 0; i < 8; i++)
        #pragma unroll
        for (int j = 0; j < 8; j++) acc[i][j] = 0.f;

    for (int k0 = 0; k0 < Kd; k0 += BK) {
        {
            int row = tid >> 2, c4 = tid & 3;
            float4 v0 = *(const float4*)&X[(long)(bm + row) * Kd + k0 + c4 * 4];
            float4 v1 = *(const float4*)&X[(long)(bm + row + 64) * Kd + k0 + c4 * 4];
            As[c4 * 4 + 0][row] = v0.x; As[c4 * 4 + 1][row] = v0.y;
            As[c4 * 4 + 2][row] = v0.z; As[c4 * 4 + 3][row] = v0.w;
            As[c4 * 4 + 0][row + 64] = v1.x; As[c4 * 4 + 1][row + 64] = v1.y;
            As[c4 * 4 + 2][row + 64] = v1.z; As[c4 * 4 + 3][row + 64] = v1.w;
        }
        {
            int wr = tid >> 5, wc = tid & 31;
            *(float4*)&Ws[wr][wc * 4] =
                *(const float4*)&W[(long)(k0 + wr) * N + bn + wc * 4];
            *(float4*)&Ws[wr + 8][wc * 4] =
                *(const float4*)&W[(long)(k0 + wr + 8) * N + bn + wc * 4];
        }
        __syncthreads();

        #pragma unroll
        for (int kk = 0; kk < BK; kk++) {
            float a[8], bb[8];
            *(float4*)&a[0]  = *(float4*)&As[kk][ty * 8];
            *(float4*)&a[4]  = *(float4*)&As[kk][ty * 8 + 4];
            *(float4*)&bb[0] = *(float4*)&Ws[kk][tx * 8];
            *(float4*)&bb[4] = *(float4*)&Ws[kk][tx * 8 + 4];
            #pragma unroll
            for (int i = 0; i < 8; i++)
                #pragma unroll
                for (int j = 0; j < 8; j++)
                    acc[i][j] = fmaf(a[i], bb[j], acc[i][j]);
        }
        __syncthreads();
    }

    #pragma unroll
    for (int i = 0; i < 8; i++) {
        int row = bm + ty * 8 + i;
        #pragma unroll
        for (int j = 0; j < 8; j += 4) {
            int col = bn + tx * 8 + j;
            float4 v = make_float4(acc[i][j], acc[i][j + 1], acc[i][j + 2], acc[i][j + 3]);
            *(float4*)&O[(long)row * N + col] = v;
        }
    }
}

// ------------------------- launcher ----------------------------------------
extern "C" void kernel_launch(void* const* d_in, const int* in_sizes, int n_in,
                              void* d_out, int out_size, void* d_ws, size_t ws_size,
                              hipStream_t stream)
{
    const float* x    = (const float*)d_in[0];
    const float* wq   = (const float*)d_in[1];
    const float* wk   = (const float*)d_in[2];
    const float* wv   = (const float*)d_in[3];
    const float* wo   = (const float*)d_in[4];
    const float* rel  = (const float*)d_in[5];

    u16* Qhi = (u16*)d_ws;                 // each 4,194,304 elems (8 MB)
    u16* Qlo = Qhi + 4194304;
    u16* Khi = Qlo + 4194304;
    u16* Klo = Khi + 4194304;
    u16* Vb  = Klo + 4194304;
    u16* VTp = Vb  + 4194304;
    float* ctx = (float*)(VTp + 4194304);  // 16 MB
    float* tab = ctx + 4194304;            // 256 KB

    bias_table_kernel<<<dim3(256), dim3(256), 0, stream>>>(rel, tab);
    gemm_qkv<<<dim3(8, 32, 3), dim3(256), 0, stream>>>(x, wq, wk, wv,
                                                       Qhi, Qlo, Khi, Klo, Vb);
    transpose_v<<<dim3(1024), dim3(256), 0, stream>>>(Vb, VTp);
    attn_mfma<<<dim3(1024), dim3(256), 0, stream>>>(Qhi, Qlo, Khi, Klo, VTp,
                                                    tab, ctx);
    gemm_out<<<dim3(8, 32, 1), dim3(256), 0, stream>>>(ctx, wo, (float*)d_out);
}

// Round 3
// 361.242 us; speedup vs baseline: 7.2154x; 1.9677x over previous
//
#include <hip/hip_runtime.h>
#include <hip/hip_bf16.h>

typedef __attribute__((ext_vector_type(8))) short bf16x8;
typedef __attribute__((ext_vector_type(4))) float f32x4;
typedef unsigned short u16;
typedef unsigned int u32;

#define S_LEN 2048
#define NH    16
#define DK    64
#define DMODEL 1024
#define LSTR  40   // LDS row stride (bf16) for GEMM tiles

__device__ __forceinline__ u16 f2bf(float f) {
    u32 u = __float_as_uint(f);
    return (u16)((u + 0x7FFFu + ((u >> 16) & 1u)) >> 16);
}
__device__ __forceinline__ float bf2f(u16 s) {
    return __uint_as_float(((u32)s) << 16);
}

// ------------------------- bias table --------------------------------------
__global__ __launch_bounds__(256) void bias_table_kernel(
    const float* __restrict__ rel_emb, float* __restrict__ tab)
{
    int idx = blockIdx.x * 256 + threadIdx.x;   // 0..65535
    int h = idx >> 12;
    int t = idx & 4095;
    int rp = t - 2048;          // rel_pos = k - q
    int n = -rp;                // q - k
    int ret = 0;
    if (n < 0) { ret = 16; n = -n; }
    int inner;
    if (n < 8) {
        inner = n;
    } else {
        inner = 8 + (n >= 12) + (n >= 16) + (n >= 23) + (n >= 32)
                  + (n >= 46) + (n >= 64) + (n >= 91);
        if (inner > 15) inner = 15;
    }
    tab[h * 4096 + t] = rel_emb[(ret + inner) * NH + h];
}

// ---------------- weight convert + transpose: W[k][n] -> WT hi/lo [n][k] ---
__global__ __launch_bounds__(256) void convert_wT(
    const float* __restrict__ Wq, const float* __restrict__ Wk,
    const float* __restrict__ Wv, const float* __restrict__ Wo,
    u16* __restrict__ WT)
{
    const float* src = (blockIdx.z == 0) ? Wq : (blockIdx.z == 1) ? Wk
                     : (blockIdx.z == 2) ? Wv : Wo;
    u16* hiT = WT + (long)blockIdx.z * 2097152;
    u16* loT = hiT + 1048576;
    __shared__ __align__(16) float T[64 * 68];
    const int k0 = blockIdx.y * 64, n0 = blockIdx.x * 64;
    const int tid = threadIdx.x;
    #pragma unroll
    for (int u = 0; u < 4; u++) {
        int w = tid + u * 256;
        int r = w >> 4, c4 = (w & 15) * 4;
        *(float4*)&T[r * 68 + c4] =
            *(const float4*)&src[(long)(k0 + r) * DMODEL + n0 + c4];
    }
    __syncthreads();
    #pragma unroll
    for (int u = 0; u < 4; u++) {
        int w = tid + u * 256;
        int n = w >> 4, kc = (w & 15) * 4;
        u16 hi[4], lo[4];
        #pragma unroll
        for (int j = 0; j < 4; j++) {
            float f = T[(kc + j) * 68 + n];
            hi[j] = f2bf(f);
            lo[j] = f2bf(f - bf2f(hi[j]));
        }
        *(ushort4*)&hiT[(long)(n0 + n) * DMODEL + k0 + kc] =
            make_ushort4(hi[0], hi[1], hi[2], hi[3]);
        *(ushort4*)&loT[(long)(n0 + n) * DMODEL + k0 + kc] =
            make_ushort4(lo[0], lo[1], lo[2], lo[3]);
    }
}

// ------------------------- MFMA QKV GEMM -----------------------------------
// C = X @ W, X fp32 [4096,1024] split to bf16 hi/lo during staging.
// z=0: Q (3-pass, hi/lo out), z=1: K (3-pass, hi/lo out), z=2: V (1-pass).
__global__ __launch_bounds__(256, 2) void gemm_qkv_mfma(
    const float* __restrict__ X, const u16* __restrict__ WT,
    u16* __restrict__ Qhi, u16* __restrict__ Qlo,
    u16* __restrict__ Khi, u16* __restrict__ Klo,
    u16* __restrict__ Vb)
{
    const int z = blockIdx.z;
    const u16* BhT = WT + (long)z * 2097152;
    const u16* BlT = BhT + 1048576;
    const bool full = (z != 2);

    __shared__ __align__(16) u16 Ah[128 * LSTR], Al[128 * LSTR];
    __shared__ __align__(16) u16 Bh[128 * LSTR], Bl[128 * LSTR];

    const int tid = threadIdx.x;
    const int wv = tid >> 6, lane = tid & 63;
    const int g = lane >> 4, li = lane & 15;
    const int wr = wv >> 1, wc = wv & 1;
    const int bm = blockIdx.y * 128, bn = blockIdx.x * 128;

    f32x4 acc[4][4];
    #pragma unroll
    for (int i = 0; i < 4; i++)
        #pragma unroll
        for (int j = 0; j < 4; j++) acc[i][j] = (f32x4){0.f, 0.f, 0.f, 0.f};

    for (int k0 = 0; k0 < DMODEL; k0 += 32) {
        // A staging: fp32 -> bf16 hi/lo. 128 rows x 32 k.
        #pragma unroll
        for (int u = 0; u < 4; u++) {
            int w = tid + u * 256;
            int row = w >> 3, c4 = (w & 7) * 4;
            float4 v = *(const float4*)&X[(long)(bm + row) * DMODEL + k0 + c4];
            u16 h0 = f2bf(v.x), h1 = f2bf(v.y), h2 = f2bf(v.z), h3 = f2bf(v.w);
            *(ushort4*)&Ah[row * LSTR + c4] = make_ushort4(h0, h1, h2, h3);
            if (full) {
                *(ushort4*)&Al[row * LSTR + c4] = make_ushort4(
                    f2bf(v.x - bf2f(h0)), f2bf(v.y - bf2f(h1)),
                    f2bf(v.z - bf2f(h2)), f2bf(v.w - bf2f(h3)));
            }
        }
        // B staging: pre-transposed bf16 [n][k]
        #pragma unroll
        for (int u = 0; u < 2; u++) {
            int w = tid + u * 256;
            int row = w >> 2, q8 = (w & 3) * 8;
            *(uint4*)&Bh[row * LSTR + q8] =
                *(const uint4*)&BhT[(long)(bn + row) * DMODEL + k0 + q8];
            if (full)
                *(uint4*)&Bl[row * LSTR + q8] =
                    *(const uint4*)&BlT[(long)(bn + row) * DMODEL + k0 + q8];
        }
        __syncthreads();

        bf16x8 a_h[4], b_h[4];
        #pragma unroll
        for (int i = 0; i < 4; i++)
            a_h[i] = *(const bf16x8*)&Ah[(wr * 64 + i * 16 + li) * LSTR + g * 8];
        #pragma unroll
        for (int j = 0; j < 4; j++)
            b_h[j] = *(const bf16x8*)&Bh[(wc * 64 + j * 16 + li) * LSTR + g * 8];
        #pragma unroll
        for (int i = 0; i < 4; i++)
            #pragma unroll
            for (int j = 0; j < 4; j++)
                acc[i][j] = __builtin_amdgcn_mfma_f32_16x16x32_bf16(
                    a_h[i], b_h[j], acc[i][j], 0, 0, 0);
        if (full) {
            bf16x8 a_l[4], b_l[4];
            #pragma unroll
            for (int i = 0; i < 4; i++)
                a_l[i] = *(const bf16x8*)&Al[(wr * 64 + i * 16 + li) * LSTR + g * 8];
            #pragma unroll
            for (int j = 0; j < 4; j++)
                b_l[j] = *(const bf16x8*)&Bl[(wc * 64 + j * 16 + li) * LSTR + g * 8];
            #pragma unroll
            for (int i = 0; i < 4; i++)
                #pragma unroll
                for (int j = 0; j < 4; j++) {
                    acc[i][j] = __builtin_amdgcn_mfma_f32_16x16x32_bf16(
                        a_l[i], b_h[j], acc[i][j], 0, 0, 0);
                    acc[i][j] = __builtin_amdgcn_mfma_f32_16x16x32_bf16(
                        a_h[i], b_l[j], acc[i][j], 0, 0, 0);
                }
        }
        __syncthreads();
    }

    // epilogue: scatter to [B,H,S,Dk] with hi/lo split (Q,K) or bf16 (V)
    #pragma unroll
    for (int i = 0; i < 4; i++) {
        #pragma unroll
        for (int r = 0; r < 4; r++) {
            int grow = bm + wr * 64 + i * 16 + g * 4 + r;
            int bb = grow >> 11, s = grow & 2047;
            #pragma unroll
            for (int j = 0; j < 4; j++) {
                int gcol = bn + wc * 64 + j * 16 + li;
                int hh = gcol >> 6, d = gcol & 63;
                long idx = (((long)(bb * NH + hh)) * S_LEN + s) * DK + d;
                float val = acc[i][j][r];
                if (z == 2) {
                    Vb[idx] = f2bf(val);
                } else {
                    u16 hi = f2bf(val);
                    u16* OH = (z == 0) ? Qhi : Khi;
                    u16* OL = (z == 0) ? Qlo : Klo;
                    OH[idx] = hi;
                    OL[idx] = f2bf(val - bf2f(hi));
                }
            }
        }
    }
}

// ------------------------- MFMA output GEMM --------------------------------
// O[4096,1024] fp32 = ctx(bf16) @ wo ; 1-pass bf16.
__global__ __launch_bounds__(256, 2) void gemm_out_mfma(
    const u16* __restrict__ Ab, const u16* __restrict__ WT,
    float* __restrict__ O)
{
    const u16* BhT = WT + 3L * 2097152;   // wo hi plane
    __shared__ __align__(16) u16 Ah[128 * LSTR], Bh[128 * LSTR];

    const int tid = threadIdx.x;
    const int wv = tid >> 6, lane = tid & 63;
    const int g = lane >> 4, li = lane & 15;
    const int wr = wv >> 1, wc = wv & 1;
    const int bm = blockIdx.y * 128, bn = blockIdx.x * 128;

    f32x4 acc[4][4];
    #pragma unroll
    for (int i = 0; i < 4; i++)
        #pragma unroll
        for (int j = 0; j < 4; j++) acc[i][j] = (f32x4){0.f, 0.f, 0.f, 0.f};

    for (int k0 = 0; k0 < DMODEL; k0 += 32) {
        #pragma unroll
        for (int u = 0; u < 2; u++) {
            int w = tid + u * 256;
            int row = w >> 2, q8 = (w & 3) * 8;
            *(uint4*)&Ah[row * LSTR + q8] =
                *(const uint4*)&Ab[(long)(bm + row) * DMODEL + k0 + q8];
            *(uint4*)&Bh[row * LSTR + q8] =
                *(const uint4*)&BhT[(long)(bn + row) * DMODEL + k0 + q8];
        }
        __syncthreads();

        bf16x8 a_h[4], b_h[4];
        #pragma unroll
        for (int i = 0; i < 4; i++)
            a_h[i] = *(const bf16x8*)&Ah[(wr * 64 + i * 16 + li) * LSTR + g * 8];
        #pragma unroll
        for (int j = 0; j < 4; j++)
            b_h[j] = *(const bf16x8*)&Bh[(wc * 64 + j * 16 + li) * LSTR + g * 8];
        #pragma unroll
        for (int i = 0; i < 4; i++)
            #pragma unroll
            for (int j = 0; j < 4; j++)
                acc[i][j] = __builtin_amdgcn_mfma_f32_16x16x32_bf16(
                    a_h[i], b_h[j], acc[i][j], 0, 0, 0);
        __syncthreads();
    }

    #pragma unroll
    for (int i = 0; i < 4; i++)
        #pragma unroll
        for (int r = 0; r < 4; r++) {
            int grow = bm + wr * 64 + i * 16 + g * 4 + r;
            #pragma unroll
            for (int j = 0; j < 4; j++) {
                int gcol = bn + wc * 64 + j * 16 + li;
                O[(long)grow * DMODEL + gcol] = acc[i][j][r];
            }
        }
}

// ------------------------- V transpose: [B,H,S,Dk] -> [B,H,Dk,S] -----------
__global__ __launch_bounds__(256) void transpose_v(
    const u16* __restrict__ Vb, u16* __restrict__ VT)
{
    __shared__ __align__(16) u16 t[64 * 68];
    const int blk = blockIdx.x;           // 1024 = 32 s-tiles x 32 bh
    const int st = blk & 31, bh = blk >> 5;
    const int s0 = st * 64;
    const u16* src = Vb + ((long)bh * S_LEN + s0) * DK;
    u16* dst = VT + (long)bh * DK * S_LEN;
    const int tid = threadIdx.x;

    #pragma unroll
    for (int u = 0; u < 2; u++) {
        int w = tid + u * 256;
        int s = w >> 3, c8 = (w & 7) * 8;
        ushort4 a = *(const ushort4*)&src[s * DK + c8];
        ushort4 b = *(const ushort4*)&src[s * DK + c8 + 4];
        *(ushort4*)&t[s * 68 + c8] = a;
        *(ushort4*)&t[s * 68 + c8 + 4] = b;
    }
    __syncthreads();
    #pragma unroll
    for (int u = 0; u < 2; u++) {
        int w = tid + u * 256;
        int d = w >> 3, sc8 = (w & 7) * 8;
        u16 tmp[8];
        #pragma unroll
        for (int j = 0; j < 8; j++) tmp[j] = t[(sc8 + j) * 68 + d];
        *(ushort4*)&dst[(long)d * S_LEN + s0 + sc8]     = make_ushort4(tmp[0], tmp[1], tmp[2], tmp[3]);
        *(ushort4*)&dst[(long)d * S_LEN + s0 + sc8 + 4] = make_ushort4(tmp[4], tmp[5], tmp[6], tmp[7]);
    }
}

// ------------------------- MFMA flash attention ----------------------------
#define APAD 72

__global__ __launch_bounds__(256, 4) void attn_mfma(
    const u16* __restrict__ Qhi, const u16* __restrict__ Qlo,
    const u16* __restrict__ Khi, const u16* __restrict__ Klo,
    const u16* __restrict__ VT, const float* __restrict__ tab,
    u16* __restrict__ ctxb)
{
    __shared__ __align__(16) u16 KsH[64 * APAD];
    __shared__ __align__(16) u16 KsL[64 * APAD];
    __shared__ __align__(16) u16 Vs[64 * APAD];    // [dim][key]
    __shared__ __align__(16) u16 Ps[64 * APAD];
    __shared__ float biasS[128];

    const int tid = threadIdx.x;
    const int wv = tid >> 6, lane = tid & 63;
    const int g = lane >> 4, li = lane & 15;
    const int qblk = blockIdx.x & 31;
    const int h = (blockIdx.x >> 5) & 15;
    const int b = blockIdx.x >> 9;
    const int q0 = qblk * 64;
    const long bh = b * NH + h;

    const u16* KhG = Khi + bh * (S_LEN * DK);
    const u16* KlG = Klo + bh * (S_LEN * DK);
    const u16* VtG = VT  + bh * (DK * S_LEN);
    const float* th = tab + h * 4096;

    bf16x8 qh0, qh1, ql0, ql1;
    {
        long qrow = bh * S_LEN + q0 + wv * 16 + li;
        const u16* ph = Qhi + qrow * DK + g * 8;
        const u16* pl = Qlo + qrow * DK + g * 8;
        qh0 = *(const bf16x8*)ph;  qh1 = *(const bf16x8*)(ph + 32);
        ql0 = *(const bf16x8*)pl;  ql1 = *(const bf16x8*)(pl + 32);
    }

    f32x4 Oc[4];
    float mP[4], lR[4];
    #pragma unroll
    for (int n = 0; n < 4; n++) { Oc[n] = (f32x4){0.f, 0.f, 0.f, 0.f}; }
    #pragma unroll
    for (int r = 0; r < 4; r++) { mP[r] = -1e30f; lR[r] = 0.f; }
    const int qr = wv * 16 + g * 4;

    for (int kt0 = 0; kt0 < S_LEN; kt0 += 64) {
        #pragma unroll
        for (int u = 0; u < 2; u++) {
            int w = tid + u * 256;
            int row = w >> 3, c8 = (w & 7) * 8;
            *(uint4*)&KsH[row * APAD + c8] =
                *(const uint4*)&KhG[(long)(kt0 + row) * DK + c8];
            *(uint4*)&KsL[row * APAD + c8] =
                *(const uint4*)&KlG[(long)(kt0 + row) * DK + c8];
            *(uint4*)&Vs[row * APAD + c8] =
                *(const uint4*)&VtG[(long)row * S_LEN + kt0 + c8];
        }
        if (tid < 128) {
            int idx = kt0 + tid - 63 - q0 + 2048;
            idx = idx < 0 ? 0 : (idx > 4095 ? 4095 : idx);
            biasS[tid] = th[idx];
        }
        __syncthreads();

        f32x4 Sa[4];
        #pragma unroll
        for (int n = 0; n < 4; n++) {
            const u16* kh = &KsH[(n * 16 + li) * APAD + g * 8];
            const u16* kl = &KsL[(n * 16 + li) * APAD + g * 8];
            bf16x8 bh0 = *(const bf16x8*)kh, bh1 = *(const bf16x8*)(kh + 32);
            bf16x8 bl0 = *(const bf16x8*)kl, bl1 = *(const bf16x8*)(kl + 32);
            f32x4 s = (f32x4){0.f, 0.f, 0.f, 0.f};
            s = __builtin_amdgcn_mfma_f32_16x16x32_bf16(qh0, bh0, s, 0, 0, 0);
            s = __builtin_amdgcn_mfma_f32_16x16x32_bf16(ql0, bh0, s, 0, 0, 0);
            s = __builtin_amdgcn_mfma_f32_16x16x32_bf16(qh0, bl0, s, 0, 0, 0);
            s = __builtin_amdgcn_mfma_f32_16x16x32_bf16(qh1, bh1, s, 0, 0, 0);
            s = __builtin_amdgcn_mfma_f32_16x16x32_bf16(ql1, bh1, s, 0, 0, 0);
            s = __builtin_amdgcn_mfma_f32_16x16x32_bf16(qh1, bl1, s, 0, 0, 0);
            Sa[n] = s;
        }

        #pragma unroll
        for (int n = 0; n < 4; n++)
            #pragma unroll
            for (int r = 0; r < 4; r++)
                Sa[n][r] += biasS[n * 16 + li - qr - r + 63];

        float rmx[4];
        #pragma unroll
        for (int r = 0; r < 4; r++)
            rmx[r] = fmaxf(fmaxf(Sa[0][r], Sa[1][r]), fmaxf(Sa[2][r], Sa[3][r]));
        #pragma unroll
        for (int mk = 1; mk < 16; mk <<= 1)
            #pragma unroll
            for (int r = 0; r < 4; r++)
                rmx[r] = fmaxf(rmx[r], __shfl_xor(rmx[r], mk));

        float alpha[4];
        #pragma unroll
        for (int r = 0; r < 4; r++) {
            float mn = fmaxf(mP[r], rmx[r]);
            alpha[r] = __expf(mP[r] - mn);
            mP[r] = mn;
        }
        #pragma unroll
        for (int n = 0; n < 4; n++)
            #pragma unroll
            for (int r = 0; r < 4; r++)
                Sa[n][r] = __expf(Sa[n][r] - mP[r]);

        float ls[4];
        #pragma unroll
        for (int r = 0; r < 4; r++)
            ls[r] = Sa[0][r] + Sa[1][r] + Sa[2][r] + Sa[3][r];
        #pragma unroll
        for (int mk = 1; mk < 16; mk <<= 1)
            #pragma unroll
            for (int r = 0; r < 4; r++)
                ls[r] += __shfl_xor(ls[r], mk);
        #pragma unroll
        for (int r = 0; r < 4; r++)
            lR[r] = lR[r] * alpha[r] + ls[r];
        #pragma unroll
        for (int n = 0; n < 4; n++)
            #pragma unroll
            for (int r = 0; r < 4; r++)
                Oc[n][r] *= alpha[r];

        #pragma unroll
        for (int n = 0; n < 4; n++)
            #pragma unroll
            for (int r = 0; r < 4; r++)
                Ps[(qr + r) * APAD + n * 16 + li] = f2bf(Sa[n][r]);
        __syncthreads();

        {
            const u16* pp = &Ps[(wv * 16 + li) * APAD + g * 8];
            bf16x8 p0 = *(const bf16x8*)pp, p1 = *(const bf16x8*)(pp + 32);
            #pragma unroll
            for (int n = 0; n < 4; n++) {
                const u16* vp = &Vs[(n * 16 + li) * APAD + g * 8];
                bf16x8 v0 = *(const bf16x8*)vp, v1 = *(const bf16x8*)(vp + 32);
                Oc[n] = __builtin_amdgcn_mfma_f32_16x16x32_bf16(p0, v0, Oc[n], 0, 0, 0);
                Oc[n] = __builtin_amdgcn_mfma_f32_16x16x32_bf16(p1, v1, Oc[n], 0, 0, 0);
            }
        }
        __syncthreads();
    }

    float inv[4];
    #pragma unroll
    for (int r = 0; r < 4; r++) inv[r] = 1.0f / lR[r];
    #pragma unroll
    for (int n = 0; n < 4; n++)
        #pragma unroll
        for (int r = 0; r < 4; r++)
            ctxb[((long)(b * S_LEN + q0 + qr + r)) * DMODEL + h * DK + n * 16 + li] =
                f2bf(Oc[n][r] * inv[r]);
}

// ------------------------- launcher ----------------------------------------
extern "C" void kernel_launch(void* const* d_in, const int* in_sizes, int n_in,
                              void* d_out, int out_size, void* d_ws, size_t ws_size,
                              hipStream_t stream)
{
    const float* x    = (const float*)d_in[0];
    const float* wq   = (const float*)d_in[1];
    const float* wk   = (const float*)d_in[2];
    const float* wv   = (const float*)d_in[3];
    const float* wo   = (const float*)d_in[4];
    const float* rel  = (const float*)d_in[5];

    u16* Qhi = (u16*)d_ws;                 // planes of 4,194,304 u16 (8 MB)
    u16* Qlo = Qhi + 4194304;
    u16* Khi = Qlo + 4194304;
    u16* Klo = Khi + 4194304;
    u16* Vb  = Klo + 4194304;
    u16* VT  = Vb  + 4194304;
    u16* WT  = VT  + 4194304;              // 4 weights x (hi 1M + lo 1M) u16
    u16* ctxb = WT + 8388608;              // [4096,1024] bf16
    float* tab = (float*)(ctxb + 4194304); // [16,4096] fp32

    bias_table_kernel<<<dim3(256), dim3(256), 0, stream>>>(rel, tab);
    convert_wT<<<dim3(16, 16, 4), dim3(256), 0, stream>>>(wq, wk, wv, wo, WT);
    gemm_qkv_mfma<<<dim3(8, 32, 3), dim3(256), 0, stream>>>(x, WT,
                                                            Qhi, Qlo, Khi, Klo, Vb);
    transpose_v<<<dim3(1024), dim3(256), 0, stream>>>(Vb, VT);
    attn_mfma<<<dim3(1024), dim3(256), 0, stream>>>(Qhi, Qlo, Khi, Klo, VT,
                                                    tab, ctxb);
    gemm_out_mfma<<<dim3(8, 32), dim3(256), 0, stream>>>(ctxb, WT, (float*)d_out);
}

// Round 4
// 300.493 us; speedup vs baseline: 8.6741x; 1.2022x over previous
//
#include <hip/hip_runtime.h>
#include <hip/hip_bf16.h>

typedef __attribute__((ext_vector_type(8))) short bf16x8;
typedef __attribute__((ext_vector_type(8))) _Float16 f16x8;
typedef __attribute__((ext_vector_type(4))) float f32x4;
typedef unsigned short u16;
typedef unsigned int u32;

#define S_LEN 2048
#define NH    16
#define DK    64
#define DMODEL 1024
#define LSTR  40   // LDS row stride (bf16/f16 elems) for GEMM tiles

__device__ __forceinline__ u16 f2bf(float f) {
    u32 u = __float_as_uint(f);
    return (u16)((u + 0x7FFFu + ((u >> 16) & 1u)) >> 16);
}
__device__ __forceinline__ float bf2f(u16 s) {
    return __uint_as_float(((u32)s) << 16);
}
union F16U { _Float16 h; u16 u; };
__device__ __forceinline__ u16 f2h(float f) {
    F16U v; v.h = (_Float16)f; return v.u;
}

// ------------------------- bias table --------------------------------------
__global__ __launch_bounds__(256) void bias_table_kernel(
    const float* __restrict__ rel_emb, float* __restrict__ tab)
{
    int idx = blockIdx.x * 256 + threadIdx.x;   // 0..65535
    int h = idx >> 12;
    int t = idx & 4095;
    int rp = t - 2048;          // rel_pos = k - q
    int n = -rp;                // q - k
    int ret = 0;
    if (n < 0) { ret = 16; n = -n; }
    int inner;
    if (n < 8) {
        inner = n;
    } else {
        inner = 8 + (n >= 12) + (n >= 16) + (n >= 23) + (n >= 32)
                  + (n >= 46) + (n >= 64) + (n >= 91);
        if (inner > 15) inner = 15;
    }
    tab[h * 4096 + t] = rel_emb[(ret + inner) * NH + h];
}

// ---------------- X convert: fp32 -> bf16 hi/lo planes ---------------------
__global__ __launch_bounds__(256) void convert_x(
    const float* __restrict__ X, u16* __restrict__ Xhi, u16* __restrict__ Xlo)
{
    long i8 = ((long)blockIdx.x * 256 + threadIdx.x) * 8;
    float4 a = *(const float4*)&X[i8];
    float4 b = *(const float4*)&X[i8 + 4];
    u16 h[8], l[8];
    float f[8] = {a.x, a.y, a.z, a.w, b.x, b.y, b.z, b.w};
    #pragma unroll
    for (int j = 0; j < 8; j++) {
        h[j] = f2bf(f[j]);
        l[j] = f2bf(f[j] - bf2f(h[j]));
    }
    *(ushort4*)&Xhi[i8]     = make_ushort4(h[0], h[1], h[2], h[3]);
    *(ushort4*)&Xhi[i8 + 4] = make_ushort4(h[4], h[5], h[6], h[7]);
    *(ushort4*)&Xlo[i8]     = make_ushort4(l[0], l[1], l[2], l[3]);
    *(ushort4*)&Xlo[i8 + 4] = make_ushort4(l[4], l[5], l[6], l[7]);
}

// ---------------- weight convert + transpose: W[k][n] -> WT [n][k] ---------
// z<3: bf16 hi/lo planes (wq,wk,wv). z==3: fp16 in hi plane (wo).
__global__ __launch_bounds__(256) void convert_wT(
    const float* __restrict__ Wq, const float* __restrict__ Wk,
    const float* __restrict__ Wv, const float* __restrict__ Wo,
    u16* __restrict__ WT)
{
    const float* src = (blockIdx.z == 0) ? Wq : (blockIdx.z == 1) ? Wk
                     : (blockIdx.z == 2) ? Wv : Wo;
    u16* hiT = WT + (long)blockIdx.z * 2097152;
    u16* loT = hiT + 1048576;
    const bool fp16w = (blockIdx.z == 3);
    __shared__ __align__(16) float T[64 * 68];
    const int k0 = blockIdx.y * 64, n0 = blockIdx.x * 64;
    const int tid = threadIdx.x;
    #pragma unroll
    for (int u = 0; u < 4; u++) {
        int w = tid + u * 256;
        int r = w >> 4, c4 = (w & 15) * 4;
        *(float4*)&T[r * 68 + c4] =
            *(const float4*)&src[(long)(k0 + r) * DMODEL + n0 + c4];
    }
    __syncthreads();
    #pragma unroll
    for (int u = 0; u < 4; u++) {
        int w = tid + u * 256;
        int n = w >> 4, kc = (w & 15) * 4;
        u16 hi[4], lo[4];
        #pragma unroll
        for (int j = 0; j < 4; j++) {
            float f = T[(kc + j) * 68 + n];
            if (fp16w) { hi[j] = f2h(f); lo[j] = 0; }
            else { hi[j] = f2bf(f); lo[j] = f2bf(f - bf2f(hi[j])); }
        }
        *(ushort4*)&hiT[(long)(n0 + n) * DMODEL + k0 + kc] =
            make_ushort4(hi[0], hi[1], hi[2], hi[3]);
        if (!fp16w)
            *(ushort4*)&loT[(long)(n0 + n) * DMODEL + k0 + kc] =
                make_ushort4(lo[0], lo[1], lo[2], lo[3]);
    }
}

// ------------------------- MFMA QKV GEMM -----------------------------------
// C = X @ W via bf16 hi/lo (3-pass for Q,K; 1-pass for V), fp16 outputs
// scattered to [B,H,S,Dk].
__global__ __launch_bounds__(256, 2) void gemm_qkv_mfma(
    const u16* __restrict__ Xhi, const u16* __restrict__ Xlo,
    const u16* __restrict__ WT,
    u16* __restrict__ Qf, u16* __restrict__ Kf, u16* __restrict__ Vf)
{
    const int z = blockIdx.z;
    const u16* BhT = WT + (long)z * 2097152;
    const u16* BlT = BhT + 1048576;
    const bool full = (z != 2);

    __shared__ __align__(16) u16 Ah[128 * LSTR], Al[128 * LSTR];
    __shared__ __align__(16) u16 Bh[128 * LSTR], Bl[128 * LSTR];

    const int tid = threadIdx.x;
    const int wv = tid >> 6, lane = tid & 63;
    const int g = lane >> 4, li = lane & 15;
    const int wr = wv >> 1, wc = wv & 1;
    const int bm = blockIdx.y * 128, bn = blockIdx.x * 128;

    f32x4 acc[4][4];
    #pragma unroll
    for (int i = 0; i < 4; i++)
        #pragma unroll
        for (int j = 0; j < 4; j++) acc[i][j] = (f32x4){0.f, 0.f, 0.f, 0.f};

    for (int k0 = 0; k0 < DMODEL; k0 += 32) {
        #pragma unroll
        for (int u = 0; u < 2; u++) {
            int w = tid + u * 256;
            int row = w >> 2, q8 = (w & 3) * 8;
            *(uint4*)&Ah[row * LSTR + q8] =
                *(const uint4*)&Xhi[(long)(bm + row) * DMODEL + k0 + q8];
            *(uint4*)&Bh[row * LSTR + q8] =
                *(const uint4*)&BhT[(long)(bn + row) * DMODEL + k0 + q8];
            if (full) {
                *(uint4*)&Al[row * LSTR + q8] =
                    *(const uint4*)&Xlo[(long)(bm + row) * DMODEL + k0 + q8];
                *(uint4*)&Bl[row * LSTR + q8] =
                    *(const uint4*)&BlT[(long)(bn + row) * DMODEL + k0 + q8];
            }
        }
        __syncthreads();

        bf16x8 a_h[4], b_h[4];
        #pragma unroll
        for (int i = 0; i < 4; i++)
            a_h[i] = *(const bf16x8*)&Ah[(wr * 64 + i * 16 + li) * LSTR + g * 8];
        #pragma unroll
        for (int j = 0; j < 4; j++)
            b_h[j] = *(const bf16x8*)&Bh[(wc * 64 + j * 16 + li) * LSTR + g * 8];
        #pragma unroll
        for (int i = 0; i < 4; i++)
            #pragma unroll
            for (int j = 0; j < 4; j++)
                acc[i][j] = __builtin_amdgcn_mfma_f32_16x16x32_bf16(
                    a_h[i], b_h[j], acc[i][j], 0, 0, 0);
        if (full) {
            bf16x8 a_l[4], b_l[4];
            #pragma unroll
            for (int i = 0; i < 4; i++)
                a_l[i] = *(const bf16x8*)&Al[(wr * 64 + i * 16 + li) * LSTR + g * 8];
            #pragma unroll
            for (int j = 0; j < 4; j++)
                b_l[j] = *(const bf16x8*)&Bl[(wc * 64 + j * 16 + li) * LSTR + g * 8];
            #pragma unroll
            for (int i = 0; i < 4; i++)
                #pragma unroll
                for (int j = 0; j < 4; j++) {
                    acc[i][j] = __builtin_amdgcn_mfma_f32_16x16x32_bf16(
                        a_l[i], b_h[j], acc[i][j], 0, 0, 0);
                    acc[i][j] = __builtin_amdgcn_mfma_f32_16x16x32_bf16(
                        a_h[i], b_l[j], acc[i][j], 0, 0, 0);
                }
        }
        __syncthreads();
    }

    u16* O = (z == 0) ? Qf : (z == 1) ? Kf : Vf;
    #pragma unroll
    for (int i = 0; i < 4; i++) {
        #pragma unroll
        for (int r = 0; r < 4; r++) {
            int grow = bm + wr * 64 + i * 16 + g * 4 + r;
            int bb = grow >> 11, s = grow & 2047;
            #pragma unroll
            for (int j = 0; j < 4; j++) {
                int gcol = bn + wc * 64 + j * 16 + li;
                int hh = gcol >> 6, d = gcol & 63;
                long idx = (((long)(bb * NH + hh)) * S_LEN + s) * DK + d;
                O[idx] = f2h(acc[i][j][r]);
            }
        }
    }
}

// ------------------------- MFMA output GEMM (fp16) -------------------------
__global__ __launch_bounds__(256, 2) void gemm_out_mfma(
    const u16* __restrict__ Ab, const u16* __restrict__ WT,
    float* __restrict__ O)
{
    const u16* BhT = WT + 3L * 2097152;   // wo fp16 plane
    __shared__ __align__(16) u16 Ah[128 * LSTR], Bh[128 * LSTR];

    const int tid = threadIdx.x;
    const int wv = tid >> 6, lane = tid & 63;
    const int g = lane >> 4, li = lane & 15;
    const int wr = wv >> 1, wc = wv & 1;
    const int bm = blockIdx.y * 128, bn = blockIdx.x * 128;

    f32x4 acc[4][4];
    #pragma unroll
    for (int i = 0; i < 4; i++)
        #pragma unroll
        for (int j = 0; j < 4; j++) acc[i][j] = (f32x4){0.f, 0.f, 0.f, 0.f};

    for (int k0 = 0; k0 < DMODEL; k0 += 32) {
        #pragma unroll
        for (int u = 0; u < 2; u++) {
            int w = tid + u * 256;
            int row = w >> 2, q8 = (w & 3) * 8;
            *(uint4*)&Ah[row * LSTR + q8] =
                *(const uint4*)&Ab[(long)(bm + row) * DMODEL + k0 + q8];
            *(uint4*)&Bh[row * LSTR + q8] =
                *(const uint4*)&BhT[(long)(bn + row) * DMODEL + k0 + q8];
        }
        __syncthreads();

        f16x8 a_h[4], b_h[4];
        #pragma unroll
        for (int i = 0; i < 4; i++)
            a_h[i] = *(const f16x8*)&Ah[(wr * 64 + i * 16 + li) * LSTR + g * 8];
        #pragma unroll
        for (int j = 0; j < 4; j++)
            b_h[j] = *(const f16x8*)&Bh[(wc * 64 + j * 16 + li) * LSTR + g * 8];
        #pragma unroll
        for (int i = 0; i < 4; i++)
            #pragma unroll
            for (int j = 0; j < 4; j++)
                acc[i][j] = __builtin_amdgcn_mfma_f32_16x16x32_f16(
                    a_h[i], b_h[j], acc[i][j], 0, 0, 0);
        __syncthreads();
    }

    #pragma unroll
    for (int i = 0; i < 4; i++)
        #pragma unroll
        for (int r = 0; r < 4; r++) {
            int grow = bm + wr * 64 + i * 16 + g * 4 + r;
            #pragma unroll
            for (int j = 0; j < 4; j++) {
                int gcol = bn + wc * 64 + j * 16 + li;
                O[(long)grow * DMODEL + gcol] = acc[i][j][r];
            }
        }
}

// ------------------------- V transpose: [B,H,S,Dk] -> [B,H,Dk,S] -----------
__global__ __launch_bounds__(256) void transpose_v(
    const u16* __restrict__ Vb, u16* __restrict__ VT)
{
    __shared__ __align__(16) u16 t[64 * 68];
    const int blk = blockIdx.x;           // 1024 = 32 s-tiles x 32 bh
    const int st = blk & 31, bh = blk >> 5;
    const int s0 = st * 64;
    const u16* src = Vb + ((long)bh * S_LEN + s0) * DK;
    u16* dst = VT + (long)bh * DK * S_LEN;
    const int tid = threadIdx.x;

    #pragma unroll
    for (int u = 0; u < 2; u++) {
        int w = tid + u * 256;
        int s = w >> 3, c8 = (w & 7) * 8;
        ushort4 a = *(const ushort4*)&src[s * DK + c8];
        ushort4 b = *(const ushort4*)&src[s * DK + c8 + 4];
        *(ushort4*)&t[s * 68 + c8] = a;
        *(ushort4*)&t[s * 68 + c8 + 4] = b;
    }
    __syncthreads();
    #pragma unroll
    for (int u = 0; u < 2; u++) {
        int w = tid + u * 256;
        int d = w >> 3, sc8 = (w & 7) * 8;
        u16 tmp[8];
        #pragma unroll
        for (int j = 0; j < 8; j++) tmp[j] = t[(sc8 + j) * 68 + d];
        *(ushort4*)&dst[(long)d * S_LEN + s0 + sc8]     = make_ushort4(tmp[0], tmp[1], tmp[2], tmp[3]);
        *(ushort4*)&dst[(long)d * S_LEN + s0 + sc8 + 4] = make_ushort4(tmp[4], tmp[5], tmp[6], tmp[7]);
    }
}

// ------------------------- MFMA flash attention (fp16) ---------------------
#define APAD 72

__global__ __launch_bounds__(256, 5) void attn_mfma(
    const u16* __restrict__ Qf, const u16* __restrict__ Kf,
    const u16* __restrict__ VT, const float* __restrict__ tab,
    u16* __restrict__ ctxb)
{
    __shared__ __align__(16) u16 Ks[64 * APAD];
    __shared__ __align__(16) u16 Vs[64 * APAD];    // [dim][key]
    __shared__ __align__(16) u16 Ps[64 * APAD];    // wave-private 16-row slabs
    __shared__ float biasS[128];

    const int tid = threadIdx.x;
    const int wv = tid >> 6, lane = tid & 63;
    const int g = lane >> 4, li = lane & 15;
    const int qblk = blockIdx.x & 31;
    const int h = (blockIdx.x >> 5) & 15;
    const int b = blockIdx.x >> 9;
    const int q0 = qblk * 64;
    const long bh = b * NH + h;

    const u16* KhG = Kf + bh * (S_LEN * DK);
    const u16* VtG = VT + bh * (DK * S_LEN);
    const float* th = tab + h * 4096;

    f16x8 q0f, q1f;
    {
        long qrow = bh * S_LEN + q0 + wv * 16 + li;
        const u16* ph = Qf + qrow * DK + g * 8;
        q0f = *(const f16x8*)ph;  q1f = *(const f16x8*)(ph + 32);
    }

    f32x4 Oc[4];
    float mP[4], lR[4];
    #pragma unroll
    for (int n = 0; n < 4; n++) { Oc[n] = (f32x4){0.f, 0.f, 0.f, 0.f}; }
    #pragma unroll
    for (int r = 0; r < 4; r++) { mP[r] = -1e30f; lR[r] = 0.f; }
    const int qr = wv * 16 + g * 4;

    for (int kt0 = 0; kt0 < S_LEN; kt0 += 64) {
        // ---- stage K + V^T tiles, bias slice ----
        #pragma unroll
        for (int u = 0; u < 2; u++) {
            int w = tid + u * 256;
            int row = w >> 3, c8 = (w & 7) * 8;
            *(uint4*)&Ks[row * APAD + c8] =
                *(const uint4*)&KhG[(long)(kt0 + row) * DK + c8];
            *(uint4*)&Vs[row * APAD + c8] =
                *(const uint4*)&VtG[(long)row * S_LEN + kt0 + c8];
        }
        if (tid < 128) {
            int idx = kt0 + tid - 63 - q0 + 2048;
            idx = idx < 0 ? 0 : (idx > 4095 ? 4095 : idx);
            biasS[tid] = th[idx];
        }
        __syncthreads();

        // ---- scores ----
        f32x4 Sa[4];
        #pragma unroll
        for (int n = 0; n < 4; n++) {
            const u16* kp = &Ks[(n * 16 + li) * APAD + g * 8];
            f16x8 k0 = *(const f16x8*)kp, k1 = *(const f16x8*)(kp + 32);
            f32x4 s = (f32x4){0.f, 0.f, 0.f, 0.f};
            s = __builtin_amdgcn_mfma_f32_16x16x32_f16(q0f, k0, s, 0, 0, 0);
            s = __builtin_amdgcn_mfma_f32_16x16x32_f16(q1f, k1, s, 0, 0, 0);
            Sa[n] = s;
        }

        #pragma unroll
        for (int n = 0; n < 4; n++)
            #pragma unroll
            for (int r = 0; r < 4; r++)
                Sa[n][r] += biasS[n * 16 + li - qr - r + 63];

        float rmx[4];
        #pragma unroll
        for (int r = 0; r < 4; r++)
            rmx[r] = fmaxf(fmaxf(Sa[0][r], Sa[1][r]), fmaxf(Sa[2][r], Sa[3][r]));
        #pragma unroll
        for (int mk = 1; mk < 16; mk <<= 1)
            #pragma unroll
            for (int r = 0; r < 4; r++)
                rmx[r] = fmaxf(rmx[r], __shfl_xor(rmx[r], mk));

        float alpha[4];
        #pragma unroll
        for (int r = 0; r < 4; r++) {
            float mn = fmaxf(mP[r], rmx[r]);
            alpha[r] = __expf(mP[r] - mn);
            mP[r] = mn;
        }
        #pragma unroll
        for (int n = 0; n < 4; n++)
            #pragma unroll
            for (int r = 0; r < 4; r++)
                Sa[n][r] = __expf(Sa[n][r] - mP[r]);

        float ls[4];
        #pragma unroll
        for (int r = 0; r < 4; r++)
            ls[r] = Sa[0][r] + Sa[1][r] + Sa[2][r] + Sa[3][r];
        #pragma unroll
        for (int mk = 1; mk < 16; mk <<= 1)
            #pragma unroll
            for (int r = 0; r < 4; r++)
                ls[r] += __shfl_xor(ls[r], mk);
        #pragma unroll
        for (int r = 0; r < 4; r++)
            lR[r] = lR[r] * alpha[r] + ls[r];
        #pragma unroll
        for (int n = 0; n < 4; n++)
            #pragma unroll
            for (int r = 0; r < 4; r++)
                Oc[n][r] *= alpha[r];

        // ---- P to wave-private LDS slab (no barrier needed: same-wave DS
        // ops are in-order; rows [wv*16, wv*16+16) touched only by wave wv)
        #pragma unroll
        for (int n = 0; n < 4; n++)
            #pragma unroll
            for (int r = 0; r < 4; r++)
                Ps[(qr + r) * APAD + n * 16 + li] = f2h(Sa[n][r]);

        // ---- O += P * V ----
        {
            const u16* pp = &Ps[(wv * 16 + li) * APAD + g * 8];
            f16x8 p0 = *(const f16x8*)pp, p1 = *(const f16x8*)(pp + 32);
            #pragma unroll
            for (int n = 0; n < 4; n++) {
                const u16* vp = &Vs[(n * 16 + li) * APAD + g * 8];
                f16x8 v0 = *(const f16x8*)vp, v1 = *(const f16x8*)(vp + 32);
                Oc[n] = __builtin_amdgcn_mfma_f32_16x16x32_f16(p0, v0, Oc[n], 0, 0, 0);
                Oc[n] = __builtin_amdgcn_mfma_f32_16x16x32_f16(p1, v1, Oc[n], 0, 0, 0);
            }
        }
        __syncthreads();   // all waves done with Ks/Vs before next staging
    }

    float inv[4];
    #pragma unroll
    for (int r = 0; r < 4; r++) inv[r] = 1.0f / lR[r];
    #pragma unroll
    for (int n = 0; n < 4; n++)
        #pragma unroll
        for (int r = 0; r < 4; r++)
            ctxb[((long)(b * S_LEN + q0 + qr + r)) * DMODEL + h * DK + n * 16 + li] =
                f2h(Oc[n][r] * inv[r]);
}

// ------------------------- launcher ----------------------------------------
extern "C" void kernel_launch(void* const* d_in, const int* in_sizes, int n_in,
                              void* d_out, int out_size, void* d_ws, size_t ws_size,
                              hipStream_t stream)
{
    const float* x    = (const float*)d_in[0];
    const float* wq   = (const float*)d_in[1];
    const float* wk   = (const float*)d_in[2];
    const float* wv   = (const float*)d_in[3];
    const float* wo   = (const float*)d_in[4];
    const float* rel  = (const float*)d_in[5];

    u16* W0 = (u16*)d_ws;
    u16* Qf  = W0;                          // fp16 [B,H,S,Dk]   (8 MB each)
    u16* Kf  = W0 + 4194304;
    u16* Vb  = W0 + 8388608;
    u16* VT  = W0 + 12582912;
    u16* Xhi = W0 + 16777216;               // bf16 planes of x
    u16* Xlo = W0 + 20971520;
    u16* WT  = W0 + 25165824;               // 4 x (hi 1M + lo 1M) u16 (16 MB)
    float* tab = (float*)(W0 + 33554432);   // [16,4096] fp32
    u16* ctxb = Xhi;                        // alias: Xhi dead after gemm_qkv

    bias_table_kernel<<<dim3(256), dim3(256), 0, stream>>>(rel, tab);
    convert_x<<<dim3(2048), dim3(256), 0, stream>>>(x, Xhi, Xlo);
    convert_wT<<<dim3(16, 16, 4), dim3(256), 0, stream>>>(wq, wk, wv, wo, WT);
    gemm_qkv_mfma<<<dim3(8, 32, 3), dim3(256), 0, stream>>>(Xhi, Xlo, WT,
                                                            Qf, Kf, Vb);
    transpose_v<<<dim3(1024), dim3(256), 0, stream>>>(Vb, VT);
    attn_mfma<<<dim3(1024), dim3(256), 0, stream>>>(Qf, Kf, VT, tab, ctxb);
    gemm_out_mfma<<<dim3(8, 32), dim3(256), 0, stream>>>(ctxb, WT, (float*)d_out);
}

// Round 5
// 240.959 us; speedup vs baseline: 10.8173x; 1.2471x over previous
//
#include <hip/hip_runtime.h>
#include <hip/hip_bf16.h>

typedef __attribute__((ext_vector_type(8))) _Float16 f16x8;
typedef __attribute__((ext_vector_type(4))) float f32x4;
typedef unsigned short u16;
typedef unsigned int u32;

#define S_LEN 2048
#define NH    16
#define DK    64
#define DMODEL 1024
#define LSTR  40   // LDS row stride (f16 elems) for GEMM tiles

union F16U { _Float16 h; u16 u; };
__device__ __forceinline__ u16 f2h(float f) {
    F16U v; v.h = (_Float16)f; return v.u;
}

// ------------------------- bias table --------------------------------------
// Integer-exact replica of the reference fp32 bucket math; thresholds
// {12,16,23,32,46,64,91} verified against fp32 log arithmetic.
__global__ __launch_bounds__(256) void bias_table_kernel(
    const float* __restrict__ rel_emb, float* __restrict__ tab)
{
    int idx = blockIdx.x * 256 + threadIdx.x;   // 0..65535
    int h = idx >> 12;
    int t = idx & 4095;
    int rp = t - 2048;          // rel_pos = k - q
    int n = -rp;                // q - k
    int ret = 0;
    if (n < 0) { ret = 16; n = -n; }
    int inner;
    if (n < 8) {
        inner = n;
    } else {
        inner = 8 + (n >= 12) + (n >= 16) + (n >= 23) + (n >= 32)
                  + (n >= 46) + (n >= 64) + (n >= 91);
        if (inner > 15) inner = 15;
    }
    tab[h * 4096 + t] = rel_emb[(ret + inner) * NH + h];
}

// ---------------- X convert: fp32 -> fp16 ----------------------------------
__global__ __launch_bounds__(256) void convert_x(
    const float* __restrict__ X, u16* __restrict__ Xf)
{
    long i8 = ((long)blockIdx.x * 256 + threadIdx.x) * 8;
    float4 a = *(const float4*)&X[i8];
    float4 b = *(const float4*)&X[i8 + 4];
    *(ushort4*)&Xf[i8] =
        make_ushort4(f2h(a.x), f2h(a.y), f2h(a.z), f2h(a.w));
    *(ushort4*)&Xf[i8 + 4] =
        make_ushort4(f2h(b.x), f2h(b.y), f2h(b.z), f2h(b.w));
}

// ---------------- weight convert + transpose: W[k][n] -> WT fp16 [n][k] ----
__global__ __launch_bounds__(256) void convert_wT(
    const float* __restrict__ Wq, const float* __restrict__ Wk,
    const float* __restrict__ Wv, const float* __restrict__ Wo,
    u16* __restrict__ WT)
{
    const float* src = (blockIdx.z == 0) ? Wq : (blockIdx.z == 1) ? Wk
                     : (blockIdx.z == 2) ? Wv : Wo;
    u16* dT = WT + (long)blockIdx.z * 1048576;
    __shared__ __align__(16) float T[64 * 68];
    const int k0 = blockIdx.y * 64, n0 = blockIdx.x * 64;
    const int tid = threadIdx.x;
    #pragma unroll
    for (int u = 0; u < 4; u++) {
        int w = tid + u * 256;
        int r = w >> 4, c4 = (w & 15) * 4;
        *(float4*)&T[r * 68 + c4] =
            *(const float4*)&src[(long)(k0 + r) * DMODEL + n0 + c4];
    }
    __syncthreads();
    #pragma unroll
    for (int u = 0; u < 4; u++) {
        int w = tid + u * 256;
        int n = w >> 4, kc = (w & 15) * 4;
        *(ushort4*)&dT[(long)(n0 + n) * DMODEL + k0 + kc] = make_ushort4(
            f2h(T[(kc + 0) * 68 + n]), f2h(T[(kc + 1) * 68 + n]),
            f2h(T[(kc + 2) * 68 + n]), f2h(T[(kc + 3) * 68 + n]));
    }
}

// ------------------------- MFMA QKV GEMM (fp16, 1-pass) --------------------
// z=0: Q -> [B,H,S,Dk]; z=1: K -> [B,H,S,Dk]; z=2: V -> V^T [B,H,Dk,S].
__global__ __launch_bounds__(256, 3) void gemm_qkv_mfma(
    const u16* __restrict__ Xf, const u16* __restrict__ WT,
    u16* __restrict__ Qf, u16* __restrict__ Kf, u16* __restrict__ VT)
{
    const int z = blockIdx.z;
    const u16* BT = WT + (long)z * 1048576;

    __shared__ __align__(16) u16 Ah[128 * LSTR], Bh[128 * LSTR];

    const int tid = threadIdx.x;
    const int wv = tid >> 6, lane = tid & 63;
    const int g = lane >> 4, li = lane & 15;
    const int wr = wv >> 1, wc = wv & 1;
    const int bm = blockIdx.y * 128, bn = blockIdx.x * 128;

    f32x4 acc[4][4];
    #pragma unroll
    for (int i = 0; i < 4; i++)
        #pragma unroll
        for (int j = 0; j < 4; j++) acc[i][j] = (f32x4){0.f, 0.f, 0.f, 0.f};

    for (int k0 = 0; k0 < DMODEL; k0 += 32) {
        #pragma unroll
        for (int u = 0; u < 2; u++) {
            int w = tid + u * 256;
            int row = w >> 2, q8 = (w & 3) * 8;
            *(uint4*)&Ah[row * LSTR + q8] =
                *(const uint4*)&Xf[(long)(bm + row) * DMODEL + k0 + q8];
            *(uint4*)&Bh[row * LSTR + q8] =
                *(const uint4*)&BT[(long)(bn + row) * DMODEL + k0 + q8];
        }
        __syncthreads();

        f16x8 a_h[4], b_h[4];
        #pragma unroll
        for (int i = 0; i < 4; i++)
            a_h[i] = *(const f16x8*)&Ah[(wr * 64 + i * 16 + li) * LSTR + g * 8];
        #pragma unroll
        for (int j = 0; j < 4; j++)
            b_h[j] = *(const f16x8*)&Bh[(wc * 64 + j * 16 + li) * LSTR + g * 8];
        #pragma unroll
        for (int i = 0; i < 4; i++)
            #pragma unroll
            for (int j = 0; j < 4; j++)
                acc[i][j] = __builtin_amdgcn_mfma_f32_16x16x32_f16(
                    a_h[i], b_h[j], acc[i][j], 0, 0, 0);
        __syncthreads();
    }

    if (z == 2) {
        // V^T epilogue: [B,H,Dk,S]; r-contiguous along S -> ushort4 stores
        #pragma unroll
        for (int i = 0; i < 4; i++) {
            int s_base = bm + wr * 64 + i * 16 + g * 4;
            int bb = s_base >> 11, s = s_base & 2047;
            #pragma unroll
            for (int j = 0; j < 4; j++) {
                int gcol = bn + wc * 64 + j * 16 + li;
                int hh = gcol >> 6, d = gcol & 63;
                long idx = (((long)(bb * NH + hh)) * DK + d) * S_LEN + s;
                *(ushort4*)&VT[idx] = make_ushort4(
                    f2h(acc[i][j][0]), f2h(acc[i][j][1]),
                    f2h(acc[i][j][2]), f2h(acc[i][j][3]));
            }
        }
    } else {
        u16* O = (z == 0) ? Qf : Kf;
        #pragma unroll
        for (int i = 0; i < 4; i++) {
            #pragma unroll
            for (int r = 0; r < 4; r++) {
                int grow = bm + wr * 64 + i * 16 + g * 4 + r;
                int bb = grow >> 11, s = grow & 2047;
                #pragma unroll
                for (int j = 0; j < 4; j++) {
                    int gcol = bn + wc * 64 + j * 16 + li;
                    int hh = gcol >> 6, d = gcol & 63;
                    long idx = (((long)(bb * NH + hh)) * S_LEN + s) * DK + d;
                    O[idx] = f2h(acc[i][j][r]);
                }
            }
        }
    }
}

// ------------------------- MFMA output GEMM (fp16) -------------------------
__global__ __launch_bounds__(256, 3) void gemm_out_mfma(
    const u16* __restrict__ Ab, const u16* __restrict__ WT,
    float* __restrict__ O)
{
    const u16* BT = WT + 3L * 1048576;   // wo fp16 plane
    __shared__ __align__(16) u16 Ah[128 * LSTR], Bh[128 * LSTR];

    const int tid = threadIdx.x;
    const int wv = tid >> 6, lane = tid & 63;
    const int g = lane >> 4, li = lane & 15;
    const int wr = wv >> 1, wc = wv & 1;
    const int bm = blockIdx.y * 128, bn = blockIdx.x * 128;

    f32x4 acc[4][4];
    #pragma unroll
    for (int i = 0; i < 4; i++)
        #pragma unroll
        for (int j = 0; j < 4; j++) acc[i][j] = (f32x4){0.f, 0.f, 0.f, 0.f};

    for (int k0 = 0; k0 < DMODEL; k0 += 32) {
        #pragma unroll
        for (int u = 0; u < 2; u++) {
            int w = tid + u * 256;
            int row = w >> 2, q8 = (w & 3) * 8;
            *(uint4*)&Ah[row * LSTR + q8] =
                *(const uint4*)&Ab[(long)(bm + row) * DMODEL + k0 + q8];
            *(uint4*)&Bh[row * LSTR + q8] =
                *(const uint4*)&BT[(long)(bn + row) * DMODEL + k0 + q8];
        }
        __syncthreads();

        f16x8 a_h[4], b_h[4];
        #pragma unroll
        for (int i = 0; i < 4; i++)
            a_h[i] = *(const f16x8*)&Ah[(wr * 64 + i * 16 + li) * LSTR + g * 8];
        #pragma unroll
        for (int j = 0; j < 4; j++)
            b_h[j] = *(const f16x8*)&Bh[(wc * 64 + j * 16 + li) * LSTR + g * 8];
        #pragma unroll
        for (int i = 0; i < 4; i++)
            #pragma unroll
            for (int j = 0; j < 4; j++)
                acc[i][j] = __builtin_amdgcn_mfma_f32_16x16x32_f16(
                    a_h[i], b_h[j], acc[i][j], 0, 0, 0);
        __syncthreads();
    }

    #pragma unroll
    for (int i = 0; i < 4; i++)
        #pragma unroll
        for (int r = 0; r < 4; r++) {
            int grow = bm + wr * 64 + i * 16 + g * 4 + r;
            #pragma unroll
            for (int j = 0; j < 4; j++) {
                int gcol = bn + wc * 64 + j * 16 + li;
                O[(long)grow * DMODEL + gcol] = acc[i][j][r];
            }
        }
}

// ------------------------- MFMA flash attention (fp16, S^T softmax) --------
// Scores computed transposed: S^T = K·Q^T, so C-layout gives each lane ONE
// query (col = li) and 16 keys in regs -> row-reduce = 15 in-reg ops +
// 2 shfl_xor steps (over the 4 lane-groups), vs 4-step chains per row.
#define APAD 72

__global__ __launch_bounds__(256, 5) void attn_mfma(
    const u16* __restrict__ Qf, const u16* __restrict__ Kf,
    const u16* __restrict__ VT, const float* __restrict__ tab,
    u16* __restrict__ ctxb)
{
    __shared__ __align__(16) u16 Ks[64 * APAD];
    __shared__ __align__(16) u16 Vs[64 * APAD];    // [dim][key]
    __shared__ __align__(16) u16 Ps[64 * APAD];    // [q][key], wave-private slabs
    __shared__ float biasS[128];

    const int tid = threadIdx.x;
    const int wv = tid >> 6, lane = tid & 63;
    const int g = lane >> 4, li = lane & 15;
    const int qblk = blockIdx.x & 31;
    const int h = (blockIdx.x >> 5) & 15;
    const int b = blockIdx.x >> 9;
    const int q0 = qblk * 64;
    const long bh = b * NH + h;
    const int qloc = wv * 16 + li;     // this lane's query (within block)

    const u16* KhG = Kf + bh * (S_LEN * DK);
    const u16* VtG = VT + bh * (DK * S_LEN);
    const float* th = tab + h * 4096;

    f16x8 q0f, q1f;
    {
        long qrow = bh * S_LEN + q0 + qloc;
        const u16* ph = Qf + qrow * DK + g * 8;
        q0f = *(const f16x8*)ph;  q1f = *(const f16x8*)(ph + 32);
    }

    f32x4 Oc[4];
    #pragma unroll
    for (int n = 0; n < 4; n++) Oc[n] = (f32x4){0.f, 0.f, 0.f, 0.f};
    float mP = -1e30f, lR = 0.f;

    for (int kt0 = 0; kt0 < S_LEN; kt0 += 64) {
        // ---- stage K + V^T tiles, bias slice ----
        #pragma unroll
        for (int u = 0; u < 2; u++) {
            int w = tid + u * 256;
            int row = w >> 3, c8 = (w & 7) * 8;
            *(uint4*)&Ks[row * APAD + c8] =
                *(const uint4*)&KhG[(long)(kt0 + row) * DK + c8];
            *(uint4*)&Vs[row * APAD + c8] =
                *(const uint4*)&VtG[(long)row * S_LEN + kt0 + c8];
        }
        if (tid < 128) {
            int idx = kt0 + tid - 63 - q0 + 2048;
            idx = idx < 0 ? 0 : (idx > 4095 ? 4095 : idx);
            biasS[tid] = th[idx];
        }
        __syncthreads();

        // ---- scores transposed: S^T[key][q] = K·Q^T ----
        f32x4 Sa[4];
        #pragma unroll
        for (int m = 0; m < 4; m++) {
            const u16* kp = &Ks[(m * 16 + li) * APAD + g * 8];
            f16x8 k0 = *(const f16x8*)kp, k1 = *(const f16x8*)(kp + 32);
            f32x4 s = (f32x4){0.f, 0.f, 0.f, 0.f};
            s = __builtin_amdgcn_mfma_f32_16x16x32_f16(k0, q0f, s, 0, 0, 0);
            s = __builtin_amdgcn_mfma_f32_16x16x32_f16(k1, q1f, s, 0, 0, 0);
            Sa[m] = s;   // rows: key = m*16 + g*4 + r ; col: query = li
        }

        // ---- bias (key - q + 63 indexed slice) ----
        #pragma unroll
        for (int m = 0; m < 4; m++)
            #pragma unroll
            for (int r = 0; r < 4; r++)
                Sa[m][r] += biasS[m * 16 + g * 4 + r + 63 - qloc];

        // ---- online softmax: per-lane (one query), 16 keys in regs ----
        float pm = Sa[0][0];
        #pragma unroll
        for (int m = 0; m < 4; m++)
            #pragma unroll
            for (int r = 0; r < 4; r++) pm = fmaxf(pm, Sa[m][r]);
        pm = fmaxf(pm, __shfl_xor(pm, 16));
        pm = fmaxf(pm, __shfl_xor(pm, 32));

        float mn = fmaxf(mP, pm);
        float alpha = __expf(mP - mn);
        mP = mn;

        float ls = 0.f;
        #pragma unroll
        for (int m = 0; m < 4; m++)
            #pragma unroll
            for (int r = 0; r < 4; r++) {
                Sa[m][r] = __expf(Sa[m][r] - mn);
                ls += Sa[m][r];
            }
        ls += __shfl_xor(ls, 16);
        ls += __shfl_xor(ls, 32);
        lR = lR * alpha + ls;

        // alpha for O rows (row q = g*4+r): broadcast from lane g*4+r
        float aO[4];
        #pragma unroll
        for (int r = 0; r < 4; r++) aO[r] = __shfl(alpha, g * 4 + r);
        #pragma unroll
        for (int n = 0; n < 4; n++)
            #pragma unroll
            for (int r = 0; r < 4; r++) Oc[n][r] *= aO[r];

        // ---- P -> LDS [q][key], 8B stores; wave-private rows, no barrier ----
        #pragma unroll
        for (int m = 0; m < 4; m++)
            *(ushort4*)&Ps[qloc * APAD + m * 16 + g * 4] = make_ushort4(
                f2h(Sa[m][0]), f2h(Sa[m][1]), f2h(Sa[m][2]), f2h(Sa[m][3]));

        // ---- O += P · V ----
        {
            const u16* pp = &Ps[qloc * APAD + g * 8];
            f16x8 p0 = *(const f16x8*)pp, p1 = *(const f16x8*)(pp + 32);
            #pragma unroll
            for (int n = 0; n < 4; n++) {
                const u16* vp = &Vs[(n * 16 + li) * APAD + g * 8];
                f16x8 v0 = *(const f16x8*)vp, v1 = *(const f16x8*)(vp + 32);
                Oc[n] = __builtin_amdgcn_mfma_f32_16x16x32_f16(p0, v0, Oc[n], 0, 0, 0);
                Oc[n] = __builtin_amdgcn_mfma_f32_16x16x32_f16(p1, v1, Oc[n], 0, 0, 0);
            }
        }
        __syncthreads();   // all waves done with Ks/Vs before next staging
    }

    float linv = 1.0f / lR;
    float iv[4];
    #pragma unroll
    for (int r = 0; r < 4; r++) iv[r] = __shfl(linv, g * 4 + r);
    #pragma unroll
    for (int n = 0; n < 4; n++)
        #pragma unroll
        for (int r = 0; r < 4; r++)
            ctxb[((long)(b * S_LEN + q0 + wv * 16 + g * 4 + r)) * DMODEL
                 + h * DK + n * 16 + li] = f2h(Oc[n][r] * iv[r]);
}

// ------------------------- launcher ----------------------------------------
extern "C" void kernel_launch(void* const* d_in, const int* in_sizes, int n_in,
                              void* d_out, int out_size, void* d_ws, size_t ws_size,
                              hipStream_t stream)
{
    const float* x    = (const float*)d_in[0];
    const float* wq   = (const float*)d_in[1];
    const float* wk   = (const float*)d_in[2];
    const float* wv   = (const float*)d_in[3];
    const float* wo   = (const float*)d_in[4];
    const float* rel  = (const float*)d_in[5];

    u16* W0 = (u16*)d_ws;
    u16* Xf  = W0;                          // fp16 x         (8 MB)
    u16* Qf  = W0 + 4194304;                // fp16 [B,H,S,Dk]
    u16* Kf  = W0 + 8388608;
    u16* VT  = W0 + 12582912;               // fp16 [B,H,Dk,S]
    u16* WT  = W0 + 16777216;               // 4 fp16 planes [n][k] (8 MB)
    float* tab = (float*)(W0 + 20971520);   // [16,4096] fp32
    u16* ctxb = Xf;                         // alias: Xf dead after gemm_qkv

    bias_table_kernel<<<dim3(256), dim3(256), 0, stream>>>(rel, tab);
    convert_x<<<dim3(2048), dim3(256), 0, stream>>>(x, Xf);
    convert_wT<<<dim3(16, 16, 4), dim3(256), 0, stream>>>(wq, wk, wv, wo, WT);
    gemm_qkv_mfma<<<dim3(8, 32, 3), dim3(256), 0, stream>>>(Xf, WT, Qf, Kf, VT);
    attn_mfma<<<dim3(1024), dim3(256), 0, stream>>>(Qf, Kf, VT, tab, ctxb);
    gemm_out_mfma<<<dim3(8, 32), dim3(256), 0, stream>>>(ctxb, WT, (float*)d_out);
}